// Round 9
// baseline (8177.764 us; speedup 1.0000x reference)
//
#include <hip/hip_runtime.h>
#include <cstdint>

#define TT 512

typedef unsigned short u16;
typedef uint32_t u32;
typedef float    floatx4 __attribute__((ext_vector_type(4)));
typedef _Float16 f16x8   __attribute__((ext_vector_type(8)));
typedef short    short8  __attribute__((ext_vector_type(8)));
typedef u32      u32x4   __attribute__((ext_vector_type(4)));
typedef u32      u32x2   __attribute__((ext_vector_type(2)));

__device__ __forceinline__ float sigm(float x)  { return 1.0f / (1.0f + __expf(-x)); }
__device__ __forceinline__ float tanh_(float x) { return 2.0f / (1.0f + __expf(-2.0f * x)) - 1.0f; }
__device__ __forceinline__ u16 f2h(float f) {           // f32 -> fp16 bits (RNE)
    union { _Float16 h; u16 u; } v; v.h = (_Float16)f; return v.u;
}
#define F16V(p) (*(const f16x8*)(const void*)(p))

// ---- stamped-word protocol (r7/r8-proven) + ring-4 decoupling (this round).
// r8 lesson: sampling the pacing stamp at the CURRENT parity degenerates any
// slack check into lockstep (ring-2 stamps only satisfy >= p+1 when L1 is AT
// phase p). Ring 4 + sampling parity (p-2)&3 gives L0 a 2-phase lead, so h0
// stores land at the MALL before L1 polls -> L1 first-attempt hits.
__device__ __forceinline__ void st32_dev(u32* p, u32 v) {
    asm volatile("global_store_dword %0, %1, off sc1" :: "v"(p), "v"(v) : "memory");
}
__device__ __forceinline__ void st64_dev(u32* p, u32 lo, u32 hi) {
    u32x2 d; d[0] = lo; d[1] = hi;
    asm volatile("global_store_dwordx2 %0, %1, off sc1" :: "v"(p), "v"(d) : "memory");
}
__device__ __forceinline__ u32x4 ld128_dev(const u32x4* p) {   // pipelined: no wait
    u32x4 v;
    asm volatile("global_load_dwordx4 %0, %1, off sc1" : "=v"(v) : "v"(p));
    return v;
}
__device__ __forceinline__ u32 ld32_dev(const u32* p) {        // pipelined: no wait
    u32 v;
    asm volatile("global_load_dword %0, %1, off sc1" : "=v"(v) : "v"(p));
    return v;
}
__device__ __forceinline__ void vmcnt0() { asm volatile("s_waitcnt vmcnt(0)" ::: "memory"); }
#define KEEP(x) asm volatile("" : "+v"(x))   // consume-after-wait fence (rule #18)

// zero stamps each launch (stale stamps 1..513 would false-accept).
// hx0 (1MB) + hx1 (1MB) + posc (128KB) contiguous = 139264 dwordx4.
__global__ void zero_ws(u32* base, int n4) {
    u32x4 z = {0u, 0u, 0u, 0u};
    for (int i = blockIdx.x * blockDim.x + threadIdx.x; i < n4; i += gridDim.x * blockDim.x)
        asm volatile("global_store_dwordx4 %0, %1, off sc1"
                     :: "v"(((u32x4*)base) + i), "v"(z) : "memory");
}

#define MFMA_(A_, B_, ACC) ACC = __builtin_amdgcn_mfma_f32_16x16x32_f16(A_, B_, ACC, 0, 0, 0)
#define MS1(ACC, GATE_) { f16x8 A_ = F16V(fs0 + (GATE_) * 4096); MFMA_(A_, Bh, ACC); }
#define MS3(ACC, GATE_) { f16x8 A1_ = F16V(fs1 + (GATE_) * 4096); MFMA_(A1_, Bh, ACC); \
    f16x8 A2_ = F16V(fs2 + (GATE_) * 4096); MFMA_(A2_, Ch, ACC); }

#define GATE0(R) { \
    const int d_ = dg16 + 4 * q + (R); \
    float zi_ = Zi[R] + bs[0][d_], zf_ = Zf[R] + bs[1][d_]; \
    float zg_ = Zg[R] + bs[2][d_], zo_ = Zo[R] + bs[3][d_]; \
    float c_  = sigm(zf_) * cv[R] + sigm(zi_) * tanh_(zg_); cv[R] = c_; \
    float hv_ = sigm(zo_) * tanh_(c_); \
    st32_dev(&hx0w[d_ * 16 + bq], tgthi | (u32)f2h(hv_)); }
#define GATE1(R) { \
    const int d_ = dg16 + 4 * q + (R); \
    float zi_ = Yi[R] + bs[0][d_], zf_ = Yf[R] + bs[1][d_]; \
    float zg_ = Yg[R] + bs[2][d_], zo_ = Yo[R] + bs[3][d_]; \
    float c_  = sigm(zf_) * cv[R] + sigm(zi_) * tanh_(zg_); cv[R] = c_; \
    float hv_ = sigm(zo_) * tanh_(c_); \
    st32_dev(&hx1w[d_ * 16 + bq], tgthi | (u32)f2h(hv_)); \
    part += hv_ * who_s[d_]; }

#define UNPACK0(v, i4) { const int d_ = (i4) >> 2, bb_ = ((i4) & 3) * 4; \
    h0f[bb_ + 0][d_] = (u16)((v)[0] & 0xFFFFu); \
    h0f[bb_ + 1][d_] = (u16)((v)[1] & 0xFFFFu); \
    h0f[bb_ + 2][d_] = (u16)((v)[2] & 0xFFFFu); \
    h0f[bb_ + 3][d_] = (u16)((v)[3] & 0xFFFFu); }
#define UNPACK1(v, i4) { const int d_ = (i4) >> 2, bb_ = ((i4) & 3) * 4; \
    h1f[bb_ + 0][d_] = (u16)((v)[0] & 0xFFFFu); \
    h1f[bb_ + 1][d_] = (u16)((v)[1] & 0xFFFFu); \
    h1f[bb_ + 2][d_] = (u16)((v)[2] & 0xFFFFu); \
    h1f[bb_ + 3][d_] = (u16)((v)[3] & 0xFFFFu); }
#define STALE4(v) (((v)[0] ^ tgthi) | ((v)[1] ^ tgthi) | ((v)[2] ^ tgthi) | ((v)[3] ^ tgthi))

// 256 blocks = 16 groups x (8 L0-slices + 8 L1-slices), 128 threads, 1/CU.
// Rings: hx0/hx1/posc 4-parity (p&3). Skew bounds: L0 cohort <=1 (exact-match
// full hx0 read), L1 cohort <=1 (exact-match full hx1 read), L0 ahead of L1
// <=3 (pacing: L0 at p requires L1 stamp >= p-1 sampled at parity (p-2)&3).
// Overwrite at P kills h0(P-3); last reader is L1 at P-4; guard (checked at
// P-1) gives L1 >= P-3 > P-4 done. All exact-match stamp checks stay valid
// since max skew 3 < ring 4.
__launch_bounds__(128, 1)
__global__ void lstm_wave(const float* __restrict__ latent, const float* __restrict__ W_lh,
                          const float* __restrict__ b_lh,
                          const float* __restrict__ W_hh0,
                          const float* __restrict__ b_ih0, const float* __restrict__ b_hh0,
                          const float* __restrict__ W_ih1, const float* __restrict__ W_hh1,
                          const float* __restrict__ b_ih1, const float* __restrict__ b_hh1,
                          const float* __restrict__ W_ho,  const float* __restrict__ b_ho,
                          u32* __restrict__ hx0, u32* __restrict__ hx1,
                          u32* __restrict__ posc, float* __restrict__ out)
{
    extern __shared__ __align__(16) char smem[];
    short* wlds     = (short*)smem;                          // <=128KB weight frags
    u16 (*h0f)[264] = (u16(*)[264])(smem + 131072);          // 8448 B
    u16 (*h1f)[264] = (u16(*)[264])(smem + 139520);          // 8448 B (L1 only)
    float (*bs)[256] = (float(*)[256])(smem + 147968);       // 4096 B (b0 or b1)
    float* who_s    = (float*)(smem + 152064);               // 1024 B (L1 only)

    const int tid  = threadIdx.x;      // 128 threads, 2 waves
    const int w    = tid >> 6;
    const int lane = tid & 63;
    const int bq   = lane & 15;
    const int q    = lane >> 4;
    const int g    = blockIdx.x & 15;  // batch group
    const int s16  = blockIdx.x >> 4;  // 0..15
    const int role = s16 >> 3;         // 0 = layer-0 block, 1 = layer-1 block
    const int jl   = s16 & 7;          // 32-dim slice within the layer
    const int bglo = g * 16;

    // ---- stage this block's weight slice f32->f16 into LDS (one-time)
    {
        const int nv = role ? 8192 : 4096;       // 8-float vectors
        for (int i = tid; i < nv; i += 128) {
            const int l8 = i & 63, s8 = (i >> 6) & 7, gate8 = (i >> 9) & 3;
            const int dgl = (i >> 11) & 1, G = (i >> 12) & 1;
            const float* W = role ? (G ? W_hh1 : W_ih1) : W_hh0;
            const int rowdim = jl * 32 + dgl * 16 + (l8 & 15);
            const float* src = W + (gate8 * 256 + rowdim) * 256 + s8 * 32 + (l8 >> 4) * 8;
            short8 v;
#pragma unroll
            for (int jj = 0; jj < 8; ++jj) v[jj] = (short)f2h(src[jj]);
            *(short8*)(wlds + l8 * 8 + s8 * 512 + gate8 * 4096 + dgl * 16384 + G * 32768) = v;
        }
    }
    for (int i = tid; i < 1024; i += 128)
        bs[i >> 8][i & 255] = role ? (b_ih1[i] + b_hh1[i]) : (b_ih0[i] + b_hh0[i]);
    if (role) { who_s[tid] = W_ho[tid]; who_s[tid + 128] = W_ho[tid + 128]; }

    // ---- h_init = latent @ W_lh.T + b_lh (fp32), rounded to fp16
    {
        const int b = tid >> 3, d0 = (tid & 7) * 32;
        const float* lr = latent + (bglo + b) * 128;
        for (int jj = 0; jj < 32; ++jj) {
            const int d = d0 + jj;
            const float* wr = W_lh + d * 128;
            float acc = b_lh[d];
            for (int c = 0; c < 128; c += 4) {
                float4 lv = *(const float4*)(lr + c);
                float4 wv = *(const float4*)(wr + c);
                acc += lv.x * wv.x + lv.y * wv.y + lv.z * wv.z + lv.w * wv.w;
            }
            u16 hb = f2h(acc);
            h0f[b][d] = hb;
            if (role) h1f[b][d] = hb;
        }
    }
    __syncthreads();

    const int dg16 = jl * 32 + w * 16;
    const short* fbA = wlds + w * 16384 + (size_t)lane * 8;  // L0: W_hh0; L1: W_ih1
    float cv[4] = {0.f, 0.f, 0.f, 0.f};
    const float bho = b_ho[0];
    const unsigned long long ALL = 0xFFFFFFFFFFFFFFFFull;

    if (role == 0) {
        // ================= layer-0 block: phases 0..TT-1 =================
        for (int p = 0; p < TT; ++p) {
            const int pb = p & 3;
            u32* hx0w = hx0 + pb * 65536 + g * 4096;
            const u32 tgthi = (u32)(p + 1) << 16;
            const u32 tgt32 = (u32)(p + 1);

            floatx4 Zi = {0.f,0.f,0.f,0.f}, Zf = {0.f,0.f,0.f,0.f};
            floatx4 Zg = {0.f,0.f,0.f,0.f}, Zo = {0.f,0.f,0.f,0.f};
#pragma unroll
            for (int s = 0; s < 8; ++s) {
                f16x8 Bh = F16V(&h0f[bq][s * 32 + q * 8]);
                const short* fs0 = fbA + s * 512;
                MS1(Zi, 0) MS1(Zf, 1) MS1(Zg, 2) MS1(Zo, 3)
            }
            GATE0(0) GATE0(1) GATE0(2) GATE0(3)
            if (p == TT - 1) break;          // final store issued; nothing more needed

            // readback h0(p+1) + L1-progress pacing sample at parity (p-2)&3:
            // stamps there are {p-1, p-5, ...}; monotone >= p-1 <=> L1 phase >= p-2.
            u32x4 va0, va1, va2, va3, va4, va5, va6, va7;
            u32 pc = 0;
            const u32x4* s4a = (const u32x4*)hx0w;
            const u32* pacep = hx1 + ((p - 2) & 3) * 65536 + g * 4096 + lane * 512;
            const bool dopace = (lane < 8) && (p >= 2);
#define ISSA() do { \
            va0 = ld128_dev(s4a + tid);       va1 = ld128_dev(s4a + tid + 128); \
            va2 = ld128_dev(s4a + tid + 256); va3 = ld128_dev(s4a + tid + 384); \
            va4 = ld128_dev(s4a + tid + 512); va5 = ld128_dev(s4a + tid + 640); \
            va6 = ld128_dev(s4a + tid + 768); va7 = ld128_dev(s4a + tid + 896); \
        } while (0)
            ISSA();
            if (dopace) pc = ld32_dev(pacep);
            __syncthreads();                 // both waves done reading h0f
            bool dA = false, dP = false;
            int it = 0;
            while (true) {
                vmcnt0();
                if (!dA) {
                    KEEP(va0); KEEP(va1); KEEP(va2); KEEP(va3);
                    KEEP(va4); KEEP(va5); KEEP(va6); KEEP(va7);
                    u32 sh = STALE4(va0) | STALE4(va1) | STALE4(va2) | STALE4(va3)
                           | STALE4(va4) | STALE4(va5) | STALE4(va6) | STALE4(va7);
                    if (__ballot((sh & 0xFFFF0000u) == 0u) == ALL) dA = true;
                }
                if (!dP) {
                    KEEP(pc);
                    const bool okp = dopace ? ((pc >> 16) + 2u >= tgt32) : true;
                    if (__ballot(okp) == ALL) dP = true;
                }
                if (dA && dP) break;
                if (++it > 20000) break;     // finite-wrong, never hang
                if (!dA) ISSA();
                if (!dP && dopace) pc = ld32_dev(pacep);
            }
#undef ISSA
            UNPACK0(va0, tid);       UNPACK0(va1, tid + 128);
            UNPACK0(va2, tid + 256); UNPACK0(va3, tid + 384);
            UNPACK0(va4, tid + 512); UNPACK0(va5, tid + 640);
            UNPACK0(va6, tid + 768); UNPACK0(va7, tid + 896);
            __syncthreads();                 // h0f ready for next phase
        }
    } else {
        // ================= layer-1 block: phases 0..TT =================
        const short* fbB = fbA;              // fs2 = fs1 + 32768 handles W_hh1
        const bool isout = (jl == 0);
        for (int p = 0; p <= TT; ++p) {
            const int pb = p & 3;
            const u32* hx0w = hx0 + pb * 65536 + g * 4096;
            u32* hx1w = hx1 + pb * 65536 + g * 4096;
            u32* poscw = posc + (pb * 16 + g) * 512;
            const u32 tgthi = (u32)(p + 1) << 16;
            const u32 tgt32 = (u32)(p + 1);

            if (p >= 1) {
                floatx4 Yi = {0.f,0.f,0.f,0.f}, Yf = {0.f,0.f,0.f,0.f};
                floatx4 Yg = {0.f,0.f,0.f,0.f}, Yo = {0.f,0.f,0.f,0.f};
#pragma unroll
                for (int s = 0; s < 8; ++s) {
                    f16x8 Bh = F16V(&h0f[bq][s * 32 + q * 8]);
                    f16x8 Ch = F16V(&h1f[bq][s * 32 + q * 8]);
                    const short* fs1 = fbB + s * 512;
                    const short* fs2 = fs1 + 32768;
                    MS3(Yi, 0) MS3(Yf, 1) MS3(Yg, 2) MS3(Yo, 3)
                }
                float part = 0.0f;
                GATE1(0) GATE1(1) GATE1(2) GATE1(3)
                part += __shfl_xor(part, 16, 64);
                part += __shfl_xor(part, 32, 64);
                if (q == 0)
                    st64_dev(poscw + (bq * 16 + jl * 2 + w) * 2,
                             __float_as_uint(part), tgt32);
            }

            const bool rdA = p < TT;
            const bool rdB = (p >= 1) && (p < TT);
            const bool rdP = isout && (p >= 1) && (tid < 16);
            u32x4 va0, va1, va2, va3, va4, va5, va6, va7;
            u32x4 vb0, vb1, vb2, vb3, vb4, vb5, vb6, vb7;
            u32x4 po0, po1, po2, po3, po4, po5, po6, po7;
            const u32x4* s4a = (const u32x4*)hx0w;
            const u32x4* s4b = (const u32x4*)hx1w;
            const u32x4* s4p = (const u32x4*)poscw + tid * 8;
#define ISSA() do { \
            va0 = ld128_dev(s4a + tid);       va1 = ld128_dev(s4a + tid + 128); \
            va2 = ld128_dev(s4a + tid + 256); va3 = ld128_dev(s4a + tid + 384); \
            va4 = ld128_dev(s4a + tid + 512); va5 = ld128_dev(s4a + tid + 640); \
            va6 = ld128_dev(s4a + tid + 768); va7 = ld128_dev(s4a + tid + 896); \
        } while (0)
#define ISSB() do { \
            vb0 = ld128_dev(s4b + tid);       vb1 = ld128_dev(s4b + tid + 128); \
            vb2 = ld128_dev(s4b + tid + 256); vb3 = ld128_dev(s4b + tid + 384); \
            vb4 = ld128_dev(s4b + tid + 512); vb5 = ld128_dev(s4b + tid + 640); \
            vb6 = ld128_dev(s4b + tid + 768); vb7 = ld128_dev(s4b + tid + 896); \
        } while (0)
#define ISSP() do { \
            po0 = ld128_dev(s4p);     po1 = ld128_dev(s4p + 1); \
            po2 = ld128_dev(s4p + 2); po3 = ld128_dev(s4p + 3); \
            po4 = ld128_dev(s4p + 4); po5 = ld128_dev(s4p + 5); \
            po6 = ld128_dev(s4p + 6); po7 = ld128_dev(s4p + 7); \
        } while (0)
            if (rdA) ISSA();
            if (rdB) ISSB();
            if (rdP) ISSP();
            __syncthreads();                 // both waves done reading h0f/h1f
            bool dA = !rdA, dB = !rdB, dP = !(isout && (p >= 1));
            int it = 0;
            while (true) {
                vmcnt0();
                if (!dA) {
                    KEEP(va0); KEEP(va1); KEEP(va2); KEEP(va3);
                    KEEP(va4); KEEP(va5); KEEP(va6); KEEP(va7);
                    u32 sh = STALE4(va0) | STALE4(va1) | STALE4(va2) | STALE4(va3)
                           | STALE4(va4) | STALE4(va5) | STALE4(va6) | STALE4(va7);
                    if (__ballot((sh & 0xFFFF0000u) == 0u) == ALL) dA = true;
                }
                if (!dB) {
                    KEEP(vb0); KEEP(vb1); KEEP(vb2); KEEP(vb3);
                    KEEP(vb4); KEEP(vb5); KEEP(vb6); KEEP(vb7);
                    u32 sh = STALE4(vb0) | STALE4(vb1) | STALE4(vb2) | STALE4(vb3)
                           | STALE4(vb4) | STALE4(vb5) | STALE4(vb6) | STALE4(vb7);
                    if (__ballot((sh & 0xFFFF0000u) == 0u) == ALL) dB = true;
                }
                if (!dP) {
                    u32 sf = 0;
                    if (rdP) {
                        KEEP(po0); KEEP(po1); KEEP(po2); KEEP(po3);
                        KEEP(po4); KEEP(po5); KEEP(po6); KEEP(po7);
                        sf = (po0[1] ^ tgt32) | (po0[3] ^ tgt32) | (po1[1] ^ tgt32) | (po1[3] ^ tgt32)
                           | (po2[1] ^ tgt32) | (po2[3] ^ tgt32) | (po3[1] ^ tgt32) | (po3[3] ^ tgt32)
                           | (po4[1] ^ tgt32) | (po4[3] ^ tgt32) | (po5[1] ^ tgt32) | (po5[3] ^ tgt32)
                           | (po6[1] ^ tgt32) | (po6[3] ^ tgt32) | (po7[1] ^ tgt32) | (po7[3] ^ tgt32);
                    }
                    if (__ballot(sf == 0u) == ALL) dP = true;
                }
                if (dA && dB && dP) break;
                if (++it > 20000) break;     // finite-wrong, never hang
                if (!dA) ISSA();
                if (!dB) ISSB();
                if (!dP && rdP) ISSP();
            }
#undef ISSA
#undef ISSB
#undef ISSP
            if (rdA) {
                UNPACK0(va0, tid);       UNPACK0(va1, tid + 128);
                UNPACK0(va2, tid + 256); UNPACK0(va3, tid + 384);
                UNPACK0(va4, tid + 512); UNPACK0(va5, tid + 640);
                UNPACK0(va6, tid + 768); UNPACK0(va7, tid + 896);
            }
            if (rdB) {
                UNPACK1(vb0, tid);       UNPACK1(vb1, tid + 128);
                UNPACK1(vb2, tid + 256); UNPACK1(vb3, tid + 384);
                UNPACK1(vb4, tid + 512); UNPACK1(vb5, tid + 640);
                UNPACK1(vb6, tid + 768); UNPACK1(vb7, tid + 896);
            }
            if (rdP) {                       // assemble out[t = p-1]
                float o = bho;
                o += __uint_as_float(po0[0]) + __uint_as_float(po0[2]);
                o += __uint_as_float(po1[0]) + __uint_as_float(po1[2]);
                o += __uint_as_float(po2[0]) + __uint_as_float(po2[2]);
                o += __uint_as_float(po3[0]) + __uint_as_float(po3[2]);
                o += __uint_as_float(po4[0]) + __uint_as_float(po4[2]);
                o += __uint_as_float(po5[0]) + __uint_as_float(po5[2]);
                o += __uint_as_float(po6[0]) + __uint_as_float(po6[2]);
                o += __uint_as_float(po7[0]) + __uint_as_float(po7[2]);
                out[(bglo + tid) * TT + (p - 1)] = o;
            }
            __syncthreads();                 // LDS planes ready for next phase
        }
    }
}

extern "C" void kernel_launch(void* const* d_in, const int* in_sizes, int n_in,
                              void* d_out, int out_size, void* d_ws, size_t ws_size,
                              hipStream_t stream)
{
    const float* latent = (const float*)d_in[0];
    const float* W_lh   = (const float*)d_in[1];
    const float* b_lh   = (const float*)d_in[2];
    // d_in[3] = W_ih0: unused (layer-0 inputs are all-zero)
    const float* W_hh0  = (const float*)d_in[4];
    const float* b_ih0  = (const float*)d_in[5];
    const float* b_hh0  = (const float*)d_in[6];
    const float* W_ih1  = (const float*)d_in[7];
    const float* W_hh1  = (const float*)d_in[8];
    const float* b_ih1  = (const float*)d_in[9];
    const float* b_hh1  = (const float*)d_in[10];
    const float* W_ho   = (const float*)d_in[11];
    const float* b_ho   = (const float*)d_in[12];

    char* ws = (char*)d_ws;
    u32*   hx0  = (u32*)ws;                       // 1,048,576 B (4 parities, [stamp16|f16])
    u32*   hx1  = (u32*)(ws + 1048576);           // 1,048,576 B
    u32*   posc = (u32*)(ws + 2097152);           //   131,072 B (4 par x 16g x 512 u32)
    // total 2,228,224 B

    // opt into >64KB dynamic LDS (153,088 B: 128KB wfrag + planes + biases)
    hipFuncSetAttribute((const void*)lstm_wave,
                        hipFuncAttributeMaxDynamicSharedMemorySize, 153088);

    zero_ws<<<dim3(128), dim3(256), 0, stream>>>(hx0, 139264);
    lstm_wave<<<dim3(256), dim3(128), 153088, stream>>>(latent, W_lh, b_lh,
                                                        W_hh0, b_ih0, b_hh0,
                                                        W_ih1, W_hh1, b_ih1, b_hh1,
                                                        W_ho, b_ho,
                                                        hx0, hx1, posc,
                                                        (float*)d_out);
}

// Round 10
// 2754.322 us; speedup vs baseline: 2.9691x; 2.9691x over previous
//
#include <hip/hip_runtime.h>
#include <cstdint>

#define TT 512

typedef unsigned short u16;
typedef uint32_t u32;
typedef float    floatx4 __attribute__((ext_vector_type(4)));
typedef _Float16 f16x8   __attribute__((ext_vector_type(8)));
typedef short    short8  __attribute__((ext_vector_type(8)));
typedef u32      u32x4   __attribute__((ext_vector_type(4)));
typedef u32      u32x2   __attribute__((ext_vector_type(2)));

__device__ __forceinline__ float sigm(float x)  { return 1.0f / (1.0f + __expf(-x)); }
__device__ __forceinline__ float tanh_(float x) { return 2.0f / (1.0f + __expf(-2.0f * x)) - 1.0f; }
__device__ __forceinline__ u16 f2h(float f) {           // f32 -> fp16 bits (RNE)
    union { _Float16 h; u16 u; } v; v.h = (_Float16)f; return v.u;
}
#define F16V(p) (*(const f16x8*)(const void*)(p))

// ---- stamped-word protocol (r7/r8-proven) + ring-4 decoupling (r9, fixed).
// r9 BUG: pacing sampled parity (p-2)&3 from p>=2, but L1's first store is
// phase 1 (parity 1) -> parity 0 stays stamp-0 until L1 phase 4 -> cross-layer
// deadlock at p=2, resolved only by the 20000-iter timeout (~5ms, the whole
// regression). Fix: pacing starts at p>=3 ("L1 stored p-2" vacuous below).
// Overwrite safety: L0 phase-P stores kill parity P&3 stamp P-3 (reader: L1
// readback P-4); pacing at end of P-1 (p>=3) => L1 stored P-3 => its P-4
// readback is done. First overwrite P=4 is guarded by the p=3 check.
__device__ __forceinline__ void st32_dev(u32* p, u32 v) {
    asm volatile("global_store_dword %0, %1, off sc1" :: "v"(p), "v"(v) : "memory");
}
__device__ __forceinline__ void st64_dev(u32* p, u32 lo, u32 hi) {
    u32x2 d; d[0] = lo; d[1] = hi;
    asm volatile("global_store_dwordx2 %0, %1, off sc1" :: "v"(p), "v"(d) : "memory");
}
__device__ __forceinline__ u32x4 ld128_dev(const u32x4* p) {   // pipelined: no wait
    u32x4 v;
    asm volatile("global_load_dwordx4 %0, %1, off sc1" : "=v"(v) : "v"(p));
    return v;
}
__device__ __forceinline__ u32 ld32_dev(const u32* p) {        // pipelined: no wait
    u32 v;
    asm volatile("global_load_dword %0, %1, off sc1" : "=v"(v) : "v"(p));
    return v;
}
__device__ __forceinline__ void vmcnt0() { asm volatile("s_waitcnt vmcnt(0)" ::: "memory"); }
#define KEEP(x) asm volatile("" : "+v"(x))   // consume-after-wait fence (rule #18)

// zero stamps each launch (stale stamps 1..513 would false-accept).
// hx0 (1MB) + hx1 (1MB) + posc (128KB) contiguous = 139264 dwordx4.
__global__ void zero_ws(u32* base, int n4) {
    u32x4 z = {0u, 0u, 0u, 0u};
    for (int i = blockIdx.x * blockDim.x + threadIdx.x; i < n4; i += gridDim.x * blockDim.x)
        asm volatile("global_store_dwordx4 %0, %1, off sc1"
                     :: "v"(((u32x4*)base) + i), "v"(z) : "memory");
}

#define MFMA_(A_, B_, ACC) ACC = __builtin_amdgcn_mfma_f32_16x16x32_f16(A_, B_, ACC, 0, 0, 0)
#define MS1(ACC, GATE_) { f16x8 A_ = F16V(fs0 + (GATE_) * 4096); MFMA_(A_, Bh, ACC); }
#define MS3(ACC, GATE_) { f16x8 A1_ = F16V(fs1 + (GATE_) * 4096); MFMA_(A1_, Bh, ACC); \
    f16x8 A2_ = F16V(fs2 + (GATE_) * 4096); MFMA_(A2_, Ch, ACC); }

#define GATE0(R) { \
    const int d_ = dg16 + 4 * q + (R); \
    float zi_ = Zi[R] + bs[0][d_], zf_ = Zf[R] + bs[1][d_]; \
    float zg_ = Zg[R] + bs[2][d_], zo_ = Zo[R] + bs[3][d_]; \
    float c_  = sigm(zf_) * cv[R] + sigm(zi_) * tanh_(zg_); cv[R] = c_; \
    float hv_ = sigm(zo_) * tanh_(c_); \
    st32_dev(&hx0w[d_ * 16 + bq], tgthi | (u32)f2h(hv_)); }
#define GATE1(R) { \
    const int d_ = dg16 + 4 * q + (R); \
    float zi_ = Yi[R] + bs[0][d_], zf_ = Yf[R] + bs[1][d_]; \
    float zg_ = Yg[R] + bs[2][d_], zo_ = Yo[R] + bs[3][d_]; \
    float c_  = sigm(zf_) * cv[R] + sigm(zi_) * tanh_(zg_); cv[R] = c_; \
    float hv_ = sigm(zo_) * tanh_(c_); \
    st32_dev(&hx1w[d_ * 16 + bq], tgthi | (u32)f2h(hv_)); \
    part += hv_ * who_s[d_]; }

#define UNPACK0(v, i4) { const int d_ = (i4) >> 2, bb_ = ((i4) & 3) * 4; \
    h0f[bb_ + 0][d_] = (u16)((v)[0] & 0xFFFFu); \
    h0f[bb_ + 1][d_] = (u16)((v)[1] & 0xFFFFu); \
    h0f[bb_ + 2][d_] = (u16)((v)[2] & 0xFFFFu); \
    h0f[bb_ + 3][d_] = (u16)((v)[3] & 0xFFFFu); }
#define UNPACK1(v, i4) { const int d_ = (i4) >> 2, bb_ = ((i4) & 3) * 4; \
    h1f[bb_ + 0][d_] = (u16)((v)[0] & 0xFFFFu); \
    h1f[bb_ + 1][d_] = (u16)((v)[1] & 0xFFFFu); \
    h1f[bb_ + 2][d_] = (u16)((v)[2] & 0xFFFFu); \
    h1f[bb_ + 3][d_] = (u16)((v)[3] & 0xFFFFu); }
#define STALE4(v) (((v)[0] ^ tgthi) | ((v)[1] ^ tgthi) | ((v)[2] ^ tgthi) | ((v)[3] ^ tgthi))

// 256 blocks = 16 groups x (8 L0-slices + 8 L1-slices), 128 threads, 1/CU.
__launch_bounds__(128, 1)
__global__ void lstm_wave(const float* __restrict__ latent, const float* __restrict__ W_lh,
                          const float* __restrict__ b_lh,
                          const float* __restrict__ W_hh0,
                          const float* __restrict__ b_ih0, const float* __restrict__ b_hh0,
                          const float* __restrict__ W_ih1, const float* __restrict__ W_hh1,
                          const float* __restrict__ b_ih1, const float* __restrict__ b_hh1,
                          const float* __restrict__ W_ho,  const float* __restrict__ b_ho,
                          u32* __restrict__ hx0, u32* __restrict__ hx1,
                          u32* __restrict__ posc, float* __restrict__ out)
{
    extern __shared__ __align__(16) char smem[];
    short* wlds     = (short*)smem;                          // <=128KB weight frags
    u16 (*h0f)[264] = (u16(*)[264])(smem + 131072);          // 8448 B
    u16 (*h1f)[264] = (u16(*)[264])(smem + 139520);          // 8448 B (L1 only)
    float (*bs)[256] = (float(*)[256])(smem + 147968);       // 4096 B (b0 or b1)
    float* who_s    = (float*)(smem + 152064);               // 1024 B (L1 only)

    const int tid  = threadIdx.x;      // 128 threads, 2 waves
    const int w    = tid >> 6;
    const int lane = tid & 63;
    const int bq   = lane & 15;
    const int q    = lane >> 4;
    const int g    = blockIdx.x & 15;  // batch group
    const int s16  = blockIdx.x >> 4;  // 0..15
    const int role = s16 >> 3;         // 0 = layer-0 block, 1 = layer-1 block
    const int jl   = s16 & 7;          // 32-dim slice within the layer
    const int bglo = g * 16;

    // ---- stage this block's weight slice f32->f16 into LDS (one-time)
    {
        const int nv = role ? 8192 : 4096;       // 8-float vectors
        for (int i = tid; i < nv; i += 128) {
            const int l8 = i & 63, s8 = (i >> 6) & 7, gate8 = (i >> 9) & 3;
            const int dgl = (i >> 11) & 1, G = (i >> 12) & 1;
            const float* W = role ? (G ? W_hh1 : W_ih1) : W_hh0;
            const int rowdim = jl * 32 + dgl * 16 + (l8 & 15);
            const float* src = W + (gate8 * 256 + rowdim) * 256 + s8 * 32 + (l8 >> 4) * 8;
            short8 v;
#pragma unroll
            for (int jj = 0; jj < 8; ++jj) v[jj] = (short)f2h(src[jj]);
            *(short8*)(wlds + l8 * 8 + s8 * 512 + gate8 * 4096 + dgl * 16384 + G * 32768) = v;
        }
    }
    for (int i = tid; i < 1024; i += 128)
        bs[i >> 8][i & 255] = role ? (b_ih1[i] + b_hh1[i]) : (b_ih0[i] + b_hh0[i]);
    if (role) { who_s[tid] = W_ho[tid]; who_s[tid + 128] = W_ho[tid + 128]; }

    // ---- h_init = latent @ W_lh.T + b_lh (fp32), rounded to fp16
    {
        const int b = tid >> 3, d0 = (tid & 7) * 32;
        const float* lr = latent + (bglo + b) * 128;
        for (int jj = 0; jj < 32; ++jj) {
            const int d = d0 + jj;
            const float* wr = W_lh + d * 128;
            float acc = b_lh[d];
            for (int c = 0; c < 128; c += 4) {
                float4 lv = *(const float4*)(lr + c);
                float4 wv = *(const float4*)(wr + c);
                acc += lv.x * wv.x + lv.y * wv.y + lv.z * wv.z + lv.w * wv.w;
            }
            u16 hb = f2h(acc);
            h0f[b][d] = hb;
            if (role) h1f[b][d] = hb;
        }
    }
    __syncthreads();

    const int dg16 = jl * 32 + w * 16;
    const short* fbA = wlds + w * 16384 + (size_t)lane * 8;  // L0: W_hh0; L1: W_ih1
    float cv[4] = {0.f, 0.f, 0.f, 0.f};
    const float bho = b_ho[0];
    const unsigned long long ALL = 0xFFFFFFFFFFFFFFFFull;

    if (role == 0) {
        // ================= layer-0 block: phases 0..TT-1 =================
        for (int p = 0; p < TT; ++p) {
            const int pb = p & 3;
            u32* hx0w = hx0 + pb * 65536 + g * 4096;
            const u32 tgthi = (u32)(p + 1) << 16;
            const u32 tgt32 = (u32)(p + 1);

            floatx4 Zi = {0.f,0.f,0.f,0.f}, Zf = {0.f,0.f,0.f,0.f};
            floatx4 Zg = {0.f,0.f,0.f,0.f}, Zo = {0.f,0.f,0.f,0.f};
#pragma unroll
            for (int s = 0; s < 8; ++s) {
                f16x8 Bh = F16V(&h0f[bq][s * 32 + q * 8]);
                const short* fs0 = fbA + s * 512;
                MS1(Zi, 0) MS1(Zf, 1) MS1(Zg, 2) MS1(Zo, 3)
            }
            GATE0(0) GATE0(1) GATE0(2) GATE0(3)
            if (p == TT - 1) break;          // final store issued; nothing more needed

            // readback h0(p+1) + L1-progress pacing at parity (p-2)&3:
            // stamps there are {p-1, p-5, ...}; >= p-1 <=> L1 stored phase p-2.
            // p>=3 ONLY (p-2>=1; L1 never stores phase 0 -- the r9 deadlock).
            u32x4 va0, va1, va2, va3, va4, va5, va6, va7;
            u32 pc = 0;
            const u32x4* s4a = (const u32x4*)hx0w;
            const u32* pacep = hx1 + ((p - 2) & 3) * 65536 + g * 4096 + lane * 512;
            const bool dopace = (lane < 8) && (p >= 3);
#define ISSA() do { \
            va0 = ld128_dev(s4a + tid);       va1 = ld128_dev(s4a + tid + 128); \
            va2 = ld128_dev(s4a + tid + 256); va3 = ld128_dev(s4a + tid + 384); \
            va4 = ld128_dev(s4a + tid + 512); va5 = ld128_dev(s4a + tid + 640); \
            va6 = ld128_dev(s4a + tid + 768); va7 = ld128_dev(s4a + tid + 896); \
        } while (0)
            ISSA();
            if (dopace) pc = ld32_dev(pacep);
            __syncthreads();                 // both waves done reading h0f
            bool dA = false, dP = false;
            int it = 0;
            while (true) {
                vmcnt0();
                if (!dA) {
                    KEEP(va0); KEEP(va1); KEEP(va2); KEEP(va3);
                    KEEP(va4); KEEP(va5); KEEP(va6); KEEP(va7);
                    u32 sh = STALE4(va0) | STALE4(va1) | STALE4(va2) | STALE4(va3)
                           | STALE4(va4) | STALE4(va5) | STALE4(va6) | STALE4(va7);
                    if (__ballot((sh & 0xFFFF0000u) == 0u) == ALL) dA = true;
                }
                if (!dP) {
                    KEEP(pc);
                    const bool okp = dopace ? ((pc >> 16) + 2u >= tgt32) : true;
                    if (__ballot(okp) == ALL) dP = true;
                }
                if (dA && dP) break;
                if (++it > 20000) break;     // finite-wrong, never hang
                if (it > 64) __builtin_amdgcn_s_sleep(1);   // backoff: don't hammer MALL
                if (!dA) ISSA();
                if (!dP && dopace) pc = ld32_dev(pacep);
            }
#undef ISSA
            UNPACK0(va0, tid);       UNPACK0(va1, tid + 128);
            UNPACK0(va2, tid + 256); UNPACK0(va3, tid + 384);
            UNPACK0(va4, tid + 512); UNPACK0(va5, tid + 640);
            UNPACK0(va6, tid + 768); UNPACK0(va7, tid + 896);
            __syncthreads();                 // h0f ready for next phase
        }
    } else {
        // ================= layer-1 block: phases 0..TT =================
        const short* fbB = fbA;              // fs2 = fs1 + 32768 handles W_hh1
        const bool isout = (jl == 0);
        for (int p = 0; p <= TT; ++p) {
            const int pb = p & 3;
            const u32* hx0w = hx0 + pb * 65536 + g * 4096;
            u32* hx1w = hx1 + pb * 65536 + g * 4096;
            u32* poscw = posc + (pb * 16 + g) * 512;
            const u32 tgthi = (u32)(p + 1) << 16;
            const u32 tgt32 = (u32)(p + 1);

            if (p >= 1) {
                floatx4 Yi = {0.f,0.f,0.f,0.f}, Yf = {0.f,0.f,0.f,0.f};
                floatx4 Yg = {0.f,0.f,0.f,0.f}, Yo = {0.f,0.f,0.f,0.f};
#pragma unroll
                for (int s = 0; s < 8; ++s) {
                    f16x8 Bh = F16V(&h0f[bq][s * 32 + q * 8]);
                    f16x8 Ch = F16V(&h1f[bq][s * 32 + q * 8]);
                    const short* fs1 = fbB + s * 512;
                    const short* fs2 = fs1 + 32768;
                    MS3(Yi, 0) MS3(Yf, 1) MS3(Yg, 2) MS3(Yo, 3)
                }
                float part = 0.0f;
                GATE1(0) GATE1(1) GATE1(2) GATE1(3)
                part += __shfl_xor(part, 16, 64);
                part += __shfl_xor(part, 32, 64);
                if (q == 0)
                    st64_dev(poscw + (bq * 16 + jl * 2 + w) * 2,
                             __float_as_uint(part), tgt32);
            }

            const bool rdA = p < TT;
            const bool rdB = (p >= 1) && (p < TT);
            const bool rdP = isout && (p >= 1) && (tid < 16);
            u32x4 va0, va1, va2, va3, va4, va5, va6, va7;
            u32x4 vb0, vb1, vb2, vb3, vb4, vb5, vb6, vb7;
            u32x4 po0, po1, po2, po3, po4, po5, po6, po7;
            const u32x4* s4a = (const u32x4*)hx0w;
            const u32x4* s4b = (const u32x4*)hx1w;
            const u32x4* s4p = (const u32x4*)poscw + tid * 8;
#define ISSA() do { \
            va0 = ld128_dev(s4a + tid);       va1 = ld128_dev(s4a + tid + 128); \
            va2 = ld128_dev(s4a + tid + 256); va3 = ld128_dev(s4a + tid + 384); \
            va4 = ld128_dev(s4a + tid + 512); va5 = ld128_dev(s4a + tid + 640); \
            va6 = ld128_dev(s4a + tid + 768); va7 = ld128_dev(s4a + tid + 896); \
        } while (0)
#define ISSB() do { \
            vb0 = ld128_dev(s4b + tid);       vb1 = ld128_dev(s4b + tid + 128); \
            vb2 = ld128_dev(s4b + tid + 256); vb3 = ld128_dev(s4b + tid + 384); \
            vb4 = ld128_dev(s4b + tid + 512); vb5 = ld128_dev(s4b + tid + 640); \
            vb6 = ld128_dev(s4b + tid + 768); vb7 = ld128_dev(s4b + tid + 896); \
        } while (0)
#define ISSP() do { \
            po0 = ld128_dev(s4p);     po1 = ld128_dev(s4p + 1); \
            po2 = ld128_dev(s4p + 2); po3 = ld128_dev(s4p + 3); \
            po4 = ld128_dev(s4p + 4); po5 = ld128_dev(s4p + 5); \
            po6 = ld128_dev(s4p + 6); po7 = ld128_dev(s4p + 7); \
        } while (0)
            if (rdA) ISSA();
            if (rdB) ISSB();
            if (rdP) ISSP();
            __syncthreads();                 // both waves done reading h0f/h1f
            bool dA = !rdA, dB = !rdB, dP = !(isout && (p >= 1));
            int it = 0;
            while (true) {
                vmcnt0();
                if (!dA) {
                    KEEP(va0); KEEP(va1); KEEP(va2); KEEP(va3);
                    KEEP(va4); KEEP(va5); KEEP(va6); KEEP(va7);
                    u32 sh = STALE4(va0) | STALE4(va1) | STALE4(va2) | STALE4(va3)
                           | STALE4(va4) | STALE4(va5) | STALE4(va6) | STALE4(va7);
                    if (__ballot((sh & 0xFFFF0000u) == 0u) == ALL) dA = true;
                }
                if (!dB) {
                    KEEP(vb0); KEEP(vb1); KEEP(vb2); KEEP(vb3);
                    KEEP(vb4); KEEP(vb5); KEEP(vb6); KEEP(vb7);
                    u32 sh = STALE4(vb0) | STALE4(vb1) | STALE4(vb2) | STALE4(vb3)
                           | STALE4(vb4) | STALE4(vb5) | STALE4(vb6) | STALE4(vb7);
                    if (__ballot((sh & 0xFFFF0000u) == 0u) == ALL) dB = true;
                }
                if (!dP) {
                    u32 sf = 0;
                    if (rdP) {
                        KEEP(po0); KEEP(po1); KEEP(po2); KEEP(po3);
                        KEEP(po4); KEEP(po5); KEEP(po6); KEEP(po7);
                        sf = (po0[1] ^ tgt32) | (po0[3] ^ tgt32) | (po1[1] ^ tgt32) | (po1[3] ^ tgt32)
                           | (po2[1] ^ tgt32) | (po2[3] ^ tgt32) | (po3[1] ^ tgt32) | (po3[3] ^ tgt32)
                           | (po4[1] ^ tgt32) | (po4[3] ^ tgt32) | (po5[1] ^ tgt32) | (po5[3] ^ tgt32)
                           | (po6[1] ^ tgt32) | (po6[3] ^ tgt32) | (po7[1] ^ tgt32) | (po7[3] ^ tgt32);
                    }
                    if (__ballot(sf == 0u) == ALL) dP = true;
                }
                if (dA && dB && dP) break;
                if (++it > 20000) break;     // finite-wrong, never hang
                if (it > 64) __builtin_amdgcn_s_sleep(1);   // backoff: don't hammer MALL
                if (!dA) ISSA();
                if (!dB) ISSB();
                if (!dP && rdP) ISSP();
            }
#undef ISSA
#undef ISSB
#undef ISSP
            if (rdA) {
                UNPACK0(va0, tid);       UNPACK0(va1, tid + 128);
                UNPACK0(va2, tid + 256); UNPACK0(va3, tid + 384);
                UNPACK0(va4, tid + 512); UNPACK0(va5, tid + 640);
                UNPACK0(va6, tid + 768); UNPACK0(va7, tid + 896);
            }
            if (rdB) {
                UNPACK1(vb0, tid);       UNPACK1(vb1, tid + 128);
                UNPACK1(vb2, tid + 256); UNPACK1(vb3, tid + 384);
                UNPACK1(vb4, tid + 512); UNPACK1(vb5, tid + 640);
                UNPACK1(vb6, tid + 768); UNPACK1(vb7, tid + 896);
            }
            if (rdP) {                       // assemble out[t = p-1]
                float o = bho;
                o += __uint_as_float(po0[0]) + __uint_as_float(po0[2]);
                o += __uint_as_float(po1[0]) + __uint_as_float(po1[2]);
                o += __uint_as_float(po2[0]) + __uint_as_float(po2[2]);
                o += __uint_as_float(po3[0]) + __uint_as_float(po3[2]);
                o += __uint_as_float(po4[0]) + __uint_as_float(po4[2]);
                o += __uint_as_float(po5[0]) + __uint_as_float(po5[2]);
                o += __uint_as_float(po6[0]) + __uint_as_float(po6[2]);
                o += __uint_as_float(po7[0]) + __uint_as_float(po7[2]);
                out[(bglo + tid) * TT + (p - 1)] = o;
            }
            __syncthreads();                 // LDS planes ready for next phase
        }
    }
}

extern "C" void kernel_launch(void* const* d_in, const int* in_sizes, int n_in,
                              void* d_out, int out_size, void* d_ws, size_t ws_size,
                              hipStream_t stream)
{
    const float* latent = (const float*)d_in[0];
    const float* W_lh   = (const float*)d_in[1];
    const float* b_lh   = (const float*)d_in[2];
    // d_in[3] = W_ih0: unused (layer-0 inputs are all-zero)
    const float* W_hh0  = (const float*)d_in[4];
    const float* b_ih0  = (const float*)d_in[5];
    const float* b_hh0  = (const float*)d_in[6];
    const float* W_ih1  = (const float*)d_in[7];
    const float* W_hh1  = (const float*)d_in[8];
    const float* b_ih1  = (const float*)d_in[9];
    const float* b_hh1  = (const float*)d_in[10];
    const float* W_ho   = (const float*)d_in[11];
    const float* b_ho   = (const float*)d_in[12];

    char* ws = (char*)d_ws;
    u32*   hx0  = (u32*)ws;                       // 1,048,576 B (4 parities, [stamp16|f16])
    u32*   hx1  = (u32*)(ws + 1048576);           // 1,048,576 B
    u32*   posc = (u32*)(ws + 2097152);           //   131,072 B (4 par x 16g x 512 u32)
    // total 2,228,224 B

    // opt into >64KB dynamic LDS (153,088 B: 128KB wfrag + planes + biases)
    hipFuncSetAttribute((const void*)lstm_wave,
                        hipFuncAttributeMaxDynamicSharedMemorySize, 153088);

    zero_ws<<<dim3(128), dim3(256), 0, stream>>>(hx0, 139264);
    lstm_wave<<<dim3(256), dim3(128), 153088, stream>>>(latent, W_lh, b_lh,
                                                        W_hh0, b_ih0, b_hh0,
                                                        W_ih1, W_hh1, b_ih1, b_hh1,
                                                        W_ho, b_ho,
                                                        hx0, hx1, posc,
                                                        (float*)d_out);
}

// Round 13
// 2131.969 us; speedup vs baseline: 3.8358x; 1.2919x over previous
//
#include <hip/hip_runtime.h>
#include <cstdint>

#define TT 512

typedef unsigned short u16;
typedef uint32_t u32;
typedef float    floatx4 __attribute__((ext_vector_type(4)));
typedef _Float16 f16x8   __attribute__((ext_vector_type(8)));
typedef short    short8  __attribute__((ext_vector_type(8)));
typedef u32      u32x4   __attribute__((ext_vector_type(4)));
typedef u32      u32x2   __attribute__((ext_vector_type(2)));

__device__ __forceinline__ float sigm(float x)  { return 1.0f / (1.0f + __expf(-x)); }
__device__ __forceinline__ float tanh_(float x) { return 2.0f / (1.0f + __expf(-2.0f * x)) - 1.0f; }
__device__ __forceinline__ u16 f2h(float f) {           // f32 -> fp16 bits (RNE)
    union { _Float16 h; u16 u; } v; v.h = (_Float16)f; return v.u;
}
#define F16V(p) (*(const f16x8*)(const void*)(p))

// ---- exchange scope: FINAL (r1-r12 measured). sc1 stamped-word everywhere.
// CLOSED LINE: no HIP-visible cache-op recipe makes the XCD L2 a prompt
// cross-CU exchange medium on gfx950 (r5 null, r11 plain-store stale, r12
// sc0-store stale; r2's "correct sc0" was an artifact of 2.4ms/phase spin
// timeouts giving natural L2->MALL writeback time). Every cross-block
// handoff pays the MALL RT; the protocol minimizes HOW MANY are serialized.
// This round: a block's OWN slice no longer gates its readback (register
// bypass into the LDS plane) -- removes the zero-slack own-store RT.
__device__ __forceinline__ void st32_dev(u32* p, u32 v) {
    asm volatile("global_store_dword %0, %1, off sc1" :: "v"(p), "v"(v) : "memory");
}
__device__ __forceinline__ void st64_dev(u32* p, u32 lo, u32 hi) {
    u32x2 d; d[0] = lo; d[1] = hi;
    asm volatile("global_store_dwordx2 %0, %1, off sc1" :: "v"(p), "v"(d) : "memory");
}
__device__ __forceinline__ u32x4 ld128_dev(const u32x4* p) {   // pipelined: no wait
    u32x4 v;
    asm volatile("global_load_dwordx4 %0, %1, off sc1" : "=v"(v) : "v"(p));
    return v;
}
__device__ __forceinline__ u32 ld32_dev(const u32* p) {        // pipelined: no wait
    u32 v;
    asm volatile("global_load_dword %0, %1, off sc1" : "=v"(v) : "v"(p));
    return v;
}
__device__ __forceinline__ void vmcnt0() { asm volatile("s_waitcnt vmcnt(0)" ::: "memory"); }
#define KEEP(x) asm volatile("" : "+v"(x))   // consume-after-wait fence (rule #18)

// zero stamps each launch (stale stamps 1..513 would false-accept).
// hx0 (512KB) + hx1 (512KB) + posc (64KB) contiguous = 69632 dwordx4.
__global__ void zero_ws(u32* base, int n4) {
    u32x4 z = {0u, 0u, 0u, 0u};
    for (int i = blockIdx.x * blockDim.x + threadIdx.x; i < n4; i += gridDim.x * blockDim.x)
        asm volatile("global_store_dwordx4 %0, %1, off sc0 sc1"
                     :: "v"(((u32x4*)base) + i), "v"(z) : "memory");
}

#define MFMA_(A_, B_, ACC) ACC = __builtin_amdgcn_mfma_f32_16x16x32_f16(A_, B_, ACC, 0, 0, 0)
#define MS1(ACC, GATE_) { f16x8 A_ = F16V(fs0 + (GATE_) * 4096); MFMA_(A_, Bh, ACC); }
#define MS3(ACC, GATE_) { f16x8 A1_ = F16V(fs1 + (GATE_) * 4096); MFMA_(A1_, Bh, ACC); \
    f16x8 A2_ = F16V(fs2 + (GATE_) * 4096); MFMA_(A2_, Ch, ACC); }

#define GATE0(R) { \
    const int d_ = dg16 + 4 * q + (R); \
    float zi_ = Zi[R] + bs[0][d_], zf_ = Zf[R] + bs[1][d_]; \
    float zg_ = Zg[R] + bs[2][d_], zo_ = Zo[R] + bs[3][d_]; \
    float c_  = sigm(zf_) * cv[R] + sigm(zi_) * tanh_(zg_); cv[R] = c_; \
    float hv_ = sigm(zo_) * tanh_(c_); \
    u16 hb_ = f2h(hv_); myh[R] = hb_; \
    st32_dev(&hx0w[d_ * 16 + bq], tgthi | (u32)hb_); }
#define GATE1(R) { \
    const int d_ = dg16 + 4 * q + (R); \
    float zi_ = Yi[R] + bs[0][d_], zf_ = Yf[R] + bs[1][d_]; \
    float zg_ = Yg[R] + bs[2][d_], zo_ = Yo[R] + bs[3][d_]; \
    float c_  = sigm(zf_) * cv[R] + sigm(zi_) * tanh_(zg_); cv[R] = c_; \
    float hv_ = sigm(zo_) * tanh_(c_); \
    u16 hb_ = f2h(hv_); myh[R] = hb_; \
    st32_dev(&hx1w[d_ * 16 + bq], tgthi | (u32)hb_); \
    part += hv_ * who_s[d_]; }

#define UNPACK0(v, i4) { const int d_ = (i4) >> 2, bb_ = ((i4) & 3) * 4; \
    h0f[bb_ + 0][d_] = (u16)((v)[0] & 0xFFFFu); \
    h0f[bb_ + 1][d_] = (u16)((v)[1] & 0xFFFFu); \
    h0f[bb_ + 2][d_] = (u16)((v)[2] & 0xFFFFu); \
    h0f[bb_ + 3][d_] = (u16)((v)[3] & 0xFFFFu); }
#define UNPACK1(v, i4) { const int d_ = (i4) >> 2, bb_ = ((i4) & 3) * 4; \
    h1f[bb_ + 0][d_] = (u16)((v)[0] & 0xFFFFu); \
    h1f[bb_ + 1][d_] = (u16)((v)[1] & 0xFFFFu); \
    h1f[bb_ + 2][d_] = (u16)((v)[2] & 0xFFFFu); \
    h1f[bb_ + 3][d_] = (u16)((v)[3] & 0xFFFFu); }
#define STALE4(v) (((v)[0] ^ tgthi) | ((v)[1] ^ tgthi) | ((v)[2] ^ tgthi) | ((v)[3] ^ tgthi))

// 256 blocks = 16 groups x (8 L0-slices + 8 L1-slices), 128 threads, 1/CU.
// r8 structure verbatim (ring-2 lockstep, sc1) + own-slice register bypass:
// chunk k==jl of the readback (the block's own 32 dims) is excluded from the
// stamp check and unpack; its values go LDS-direct from registers after the
// barrier. Partners still read it from the MALL (stores unchanged).
__launch_bounds__(128, 1)
__global__ void lstm_wave(const float* __restrict__ latent, const float* __restrict__ W_lh,
                          const float* __restrict__ b_lh,
                          const float* __restrict__ W_hh0,
                          const float* __restrict__ b_ih0, const float* __restrict__ b_hh0,
                          const float* __restrict__ W_ih1, const float* __restrict__ W_hh1,
                          const float* __restrict__ b_ih1, const float* __restrict__ b_hh1,
                          const float* __restrict__ W_ho,  const float* __restrict__ b_ho,
                          u32* __restrict__ hx0, u32* __restrict__ hx1,
                          u32* __restrict__ posc, float* __restrict__ out)
{
    extern __shared__ __align__(16) char smem[];
    short* wlds     = (short*)smem;                          // <=128KB weight frags
    u16 (*h0f)[264] = (u16(*)[264])(smem + 131072);          // 8448 B
    u16 (*h1f)[264] = (u16(*)[264])(smem + 139520);          // 8448 B (L1 only)
    float (*bs)[256] = (float(*)[256])(smem + 147968);       // 4096 B (b0 or b1)
    float* who_s    = (float*)(smem + 152064);               // 1024 B (L1 only)

    const int tid  = threadIdx.x;      // 128 threads, 2 waves
    const int w    = tid >> 6;
    const int lane = tid & 63;
    const int bq   = lane & 15;
    const int q    = lane >> 4;
    const int g    = blockIdx.x & 15;  // batch group
    const int s16  = blockIdx.x >> 4;  // 0..15
    const int role = s16 >> 3;         // 0 = layer-0 block, 1 = layer-1 block
    const int jl   = s16 & 7;          // 32-dim slice within the layer
    const int bglo = g * 16;

    // ---- stage this block's weight slice f32->f16 into LDS (one-time)
    {
        const int nv = role ? 8192 : 4096;       // 8-float vectors
        for (int i = tid; i < nv; i += 128) {
            const int l8 = i & 63, s8 = (i >> 6) & 7, gate8 = (i >> 9) & 3;
            const int dgl = (i >> 11) & 1, G = (i >> 12) & 1;
            const float* W = role ? (G ? W_hh1 : W_ih1) : W_hh0;
            const int rowdim = jl * 32 + dgl * 16 + (l8 & 15);
            const float* src = W + (gate8 * 256 + rowdim) * 256 + s8 * 32 + (l8 >> 4) * 8;
            short8 v;
#pragma unroll
            for (int jj = 0; jj < 8; ++jj) v[jj] = (short)f2h(src[jj]);
            *(short8*)(wlds + l8 * 8 + s8 * 512 + gate8 * 4096 + dgl * 16384 + G * 32768) = v;
        }
    }
    for (int i = tid; i < 1024; i += 128)
        bs[i >> 8][i & 255] = role ? (b_ih1[i] + b_hh1[i]) : (b_ih0[i] + b_hh0[i]);
    if (role) { who_s[tid] = W_ho[tid]; who_s[tid + 128] = W_ho[tid + 128]; }

    // ---- h_init = latent @ W_lh.T + b_lh (fp32), rounded to fp16
    {
        const int b = tid >> 3, d0 = (tid & 7) * 32;
        const float* lr = latent + (bglo + b) * 128;
        for (int jj = 0; jj < 32; ++jj) {
            const int d = d0 + jj;
            const float* wr = W_lh + d * 128;
            float acc = b_lh[d];
            for (int c = 0; c < 128; c += 4) {
                float4 lv = *(const float4*)(lr + c);
                float4 wv = *(const float4*)(wr + c);
                acc += lv.x * wv.x + lv.y * wv.y + lv.z * wv.z + lv.w * wv.w;
            }
            u16 hb = f2h(acc);
            h0f[b][d] = hb;
            if (role) h1f[b][d] = hb;
        }
    }
    __syncthreads();

    const int dg16 = jl * 32 + w * 16;
    const short* fbA = wlds + w * 16384 + (size_t)lane * 8;  // L0: W_hh0; L1: W_ih1
    float cv[4] = {0.f, 0.f, 0.f, 0.f};
    const float bho = b_ho[0];
    const unsigned long long ALL = 0xFFFFFFFFFFFFFFFFull;
    u16 myh[4];                          // own-slice register bypass

    if (role == 0) {
        // ================= layer-0 block: phases 0..TT-1 =================
        for (int p = 0; p < TT; ++p) {
            const int pb = p & 1;
            u32* hx0w = hx0 + pb * 65536 + g * 4096;
            const u32* hx1w = hx1 + pb * 65536 + g * 4096;
            const u32 tgthi = (u32)(p + 1) << 16;
            const u32 tgt32 = (u32)(p + 1);

            floatx4 Zi = {0.f,0.f,0.f,0.f}, Zf = {0.f,0.f,0.f,0.f};
            floatx4 Zg = {0.f,0.f,0.f,0.f}, Zo = {0.f,0.f,0.f,0.f};
#pragma unroll
            for (int s = 0; s < 8; ++s) {
                f16x8 Bh = F16V(&h0f[bq][s * 32 + q * 8]);
                const short* fs0 = fbA + s * 512;
                MS1(Zi, 0) MS1(Zf, 1) MS1(Zg, 2) MS1(Zo, 3)
            }
            GATE0(0) GATE0(1) GATE0(2) GATE0(3)
            if (p == TT - 1) break;          // final store issued; nothing more needed

            // readback h0(p+1): REMOTE chunks only (k != jl) gate the check;
            // own chunk comes from registers. + lockstep pacing sample.
            u32x4 va0, va1, va2, va3, va4, va5, va6, va7;
            u32 pc = 0;
            const u32x4* s4a = (const u32x4*)hx0w;
#define ISSUE0() do { \
            va0 = ld128_dev(s4a + tid);       va1 = ld128_dev(s4a + tid + 128); \
            va2 = ld128_dev(s4a + tid + 256); va3 = ld128_dev(s4a + tid + 384); \
            va4 = ld128_dev(s4a + tid + 512); va5 = ld128_dev(s4a + tid + 640); \
            va6 = ld128_dev(s4a + tid + 768); va7 = ld128_dev(s4a + tid + 896); \
            if ((lane < 8) && p) pc = ld32_dev(hx1w + lane * 512); \
        } while (0)
            ISSUE0();
            __syncthreads();                 // both waves done reading h0f
            int it = 0;
            while (true) {
                vmcnt0();
                KEEP(va0); KEEP(va1); KEEP(va2); KEEP(va3);
                KEEP(va4); KEEP(va5); KEEP(va6); KEEP(va7); KEEP(pc);
                u32 sh = 0;
                if (jl != 0) sh |= STALE4(va0);
                if (jl != 1) sh |= STALE4(va1);
                if (jl != 2) sh |= STALE4(va2);
                if (jl != 3) sh |= STALE4(va3);
                if (jl != 4) sh |= STALE4(va4);
                if (jl != 5) sh |= STALE4(va5);
                if (jl != 6) sh |= STALE4(va6);
                if (jl != 7) sh |= STALE4(va7);
                const bool okp = ((lane < 8) && p) ? ((pc >> 16) >= tgt32) : true;
                const bool ok = ((sh & 0xFFFF0000u) == 0u) && okp;
                if (__ballot(ok) == ALL) break;
                if (++it > 20000) break;     // finite-wrong, never hang
                ISSUE0();
            }
#undef ISSUE0
            if (jl != 0) { UNPACK0(va0, tid); }
            if (jl != 1) { UNPACK0(va1, tid + 128); }
            if (jl != 2) { UNPACK0(va2, tid + 256); }
            if (jl != 3) { UNPACK0(va3, tid + 384); }
            if (jl != 4) { UNPACK0(va4, tid + 512); }
            if (jl != 5) { UNPACK0(va5, tid + 640); }
            if (jl != 6) { UNPACK0(va6, tid + 768); }
            if (jl != 7) { UNPACK0(va7, tid + 896); }
            {                                // own slice from registers
                const int db = dg16 + 4 * q;
                h0f[bq][db + 0] = myh[0]; h0f[bq][db + 1] = myh[1];
                h0f[bq][db + 2] = myh[2]; h0f[bq][db + 3] = myh[3];
            }
            __syncthreads();                 // h0f ready for next phase
        }
    } else {
        // ================= layer-1 block: phases 0..TT =================
        const short* fbB = fbA;              // fs2 = fs1 + 32768 handles W_hh1
        const bool isout = (jl == 0);
        for (int p = 0; p <= TT; ++p) {
            const int pb = p & 1;
            const u32* hx0w = hx0 + pb * 65536 + g * 4096;
            u32* hx1w = hx1 + pb * 65536 + g * 4096;
            u32* poscw = posc + (pb * 16 + g) * 512;
            const u32 tgthi = (u32)(p + 1) << 16;
            const u32 tgt32 = (u32)(p + 1);

            if (p >= 1) {
                floatx4 Yi = {0.f,0.f,0.f,0.f}, Yf = {0.f,0.f,0.f,0.f};
                floatx4 Yg = {0.f,0.f,0.f,0.f}, Yo = {0.f,0.f,0.f,0.f};
#pragma unroll
                for (int s = 0; s < 8; ++s) {
                    f16x8 Bh = F16V(&h0f[bq][s * 32 + q * 8]);
                    f16x8 Ch = F16V(&h1f[bq][s * 32 + q * 8]);
                    const short* fs1 = fbB + s * 512;
                    const short* fs2 = fs1 + 32768;
                    MS3(Yi, 0) MS3(Yf, 1) MS3(Yg, 2) MS3(Yo, 3)
                }
                float part = 0.0f;
                GATE1(0) GATE1(1) GATE1(2) GATE1(3)
                part += __shfl_xor(part, 16, 64);
                part += __shfl_xor(part, 32, 64);
                if (q == 0)
                    st64_dev(poscw + (bq * 16 + jl * 2 + w) * 2,
                             __float_as_uint(part), tgt32);
            }

            const bool rdA = p < TT;
            const bool rdB = (p >= 1) && (p < TT);
            const bool rdP = isout && (p >= 1) && (tid < 16);
            u32x4 va0, va1, va2, va3, va4, va5, va6, va7;
            u32x4 vb0, vb1, vb2, vb3, vb4, vb5, vb6, vb7;
            u32x4 po0, po1, po2, po3, po4, po5, po6, po7;
            const u32x4* s4a = (const u32x4*)hx0w;
            const u32x4* s4b = (const u32x4*)hx1w;
            const u32x4* s4p = (const u32x4*)poscw + tid * 8;
#define ISSUE1() do { \
            if (rdA) { \
                va0 = ld128_dev(s4a + tid);       va1 = ld128_dev(s4a + tid + 128); \
                va2 = ld128_dev(s4a + tid + 256); va3 = ld128_dev(s4a + tid + 384); \
                va4 = ld128_dev(s4a + tid + 512); va5 = ld128_dev(s4a + tid + 640); \
                va6 = ld128_dev(s4a + tid + 768); va7 = ld128_dev(s4a + tid + 896); } \
            if (rdB) { \
                vb0 = ld128_dev(s4b + tid);       vb1 = ld128_dev(s4b + tid + 128); \
                vb2 = ld128_dev(s4b + tid + 256); vb3 = ld128_dev(s4b + tid + 384); \
                vb4 = ld128_dev(s4b + tid + 512); vb5 = ld128_dev(s4b + tid + 640); \
                vb6 = ld128_dev(s4b + tid + 768); vb7 = ld128_dev(s4b + tid + 896); } \
            if (rdP) { \
                po0 = ld128_dev(s4p);     po1 = ld128_dev(s4p + 1); \
                po2 = ld128_dev(s4p + 2); po3 = ld128_dev(s4p + 3); \
                po4 = ld128_dev(s4p + 4); po5 = ld128_dev(s4p + 5); \
                po6 = ld128_dev(s4p + 6); po7 = ld128_dev(s4p + 7); } \
        } while (0)
            ISSUE1();
            __syncthreads();                 // both waves done reading h0f/h1f
            int it = 0;
            while (true) {
                vmcnt0();
                u32 sh = 0, sf = 0;
                if (rdA) {
                    KEEP(va0); KEEP(va1); KEEP(va2); KEEP(va3);
                    KEEP(va4); KEEP(va5); KEEP(va6); KEEP(va7);
                    sh |= STALE4(va0) | STALE4(va1) | STALE4(va2) | STALE4(va3)
                        | STALE4(va4) | STALE4(va5) | STALE4(va6) | STALE4(va7);
                }
                if (rdB) {                   // own chunk (k==jl) excluded
                    KEEP(vb0); KEEP(vb1); KEEP(vb2); KEEP(vb3);
                    KEEP(vb4); KEEP(vb5); KEEP(vb6); KEEP(vb7);
                    if (jl != 0) sh |= STALE4(vb0);
                    if (jl != 1) sh |= STALE4(vb1);
                    if (jl != 2) sh |= STALE4(vb2);
                    if (jl != 3) sh |= STALE4(vb3);
                    if (jl != 4) sh |= STALE4(vb4);
                    if (jl != 5) sh |= STALE4(vb5);
                    if (jl != 6) sh |= STALE4(vb6);
                    if (jl != 7) sh |= STALE4(vb7);
                }
                if (rdP) {
                    KEEP(po0); KEEP(po1); KEEP(po2); KEEP(po3);
                    KEEP(po4); KEEP(po5); KEEP(po6); KEEP(po7);
                    sf |= (po0[1] ^ tgt32) | (po0[3] ^ tgt32) | (po1[1] ^ tgt32) | (po1[3] ^ tgt32)
                        | (po2[1] ^ tgt32) | (po2[3] ^ tgt32) | (po3[1] ^ tgt32) | (po3[3] ^ tgt32)
                        | (po4[1] ^ tgt32) | (po4[3] ^ tgt32) | (po5[1] ^ tgt32) | (po5[3] ^ tgt32)
                        | (po6[1] ^ tgt32) | (po6[3] ^ tgt32) | (po7[1] ^ tgt32) | (po7[3] ^ tgt32);
                }
                const bool ok = ((sh & 0xFFFF0000u) == 0u) && (sf == 0u);
                if (__ballot(ok) == ALL) break;
                if (++it > 20000) break;     // finite-wrong, never hang
                ISSUE1();
            }
#undef ISSUE1
            if (rdA) {
                UNPACK0(va0, tid);       UNPACK0(va1, tid + 128);
                UNPACK0(va2, tid + 256); UNPACK0(va3, tid + 384);
                UNPACK0(va4, tid + 512); UNPACK0(va5, tid + 640);
                UNPACK0(va6, tid + 768); UNPACK0(va7, tid + 896);
            }
            if (rdB) {
                if (jl != 0) { UNPACK1(vb0, tid); }
                if (jl != 1) { UNPACK1(vb1, tid + 128); }
                if (jl != 2) { UNPACK1(vb2, tid + 256); }
                if (jl != 3) { UNPACK1(vb3, tid + 384); }
                if (jl != 4) { UNPACK1(vb4, tid + 512); }
                if (jl != 5) { UNPACK1(vb5, tid + 640); }
                if (jl != 6) { UNPACK1(vb6, tid + 768); }
                if (jl != 7) { UNPACK1(vb7, tid + 896); }
                {                            // own slice from registers
                    const int db = dg16 + 4 * q;
                    h1f[bq][db + 0] = myh[0]; h1f[bq][db + 1] = myh[1];
                    h1f[bq][db + 2] = myh[2]; h1f[bq][db + 3] = myh[3];
                }
            }
            if (rdP) {                       // assemble out[t = p-1]
                float o = bho;
                o += __uint_as_float(po0[0]) + __uint_as_float(po0[2]);
                o += __uint_as_float(po1[0]) + __uint_as_float(po1[2]);
                o += __uint_as_float(po2[0]) + __uint_as_float(po2[2]);
                o += __uint_as_float(po3[0]) + __uint_as_float(po3[2]);
                o += __uint_as_float(po4[0]) + __uint_as_float(po4[2]);
                o += __uint_as_float(po5[0]) + __uint_as_float(po5[2]);
                o += __uint_as_float(po6[0]) + __uint_as_float(po6[2]);
                o += __uint_as_float(po7[0]) + __uint_as_float(po7[2]);
                out[(bglo + tid) * TT + (p - 1)] = o;
            }
            __syncthreads();                 // LDS planes ready for next phase
        }
    }
}

extern "C" void kernel_launch(void* const* d_in, const int* in_sizes, int n_in,
                              void* d_out, int out_size, void* d_ws, size_t ws_size,
                              hipStream_t stream)
{
    const float* latent = (const float*)d_in[0];
    const float* W_lh   = (const float*)d_in[1];
    const float* b_lh   = (const float*)d_in[2];
    // d_in[3] = W_ih0: unused (layer-0 inputs are all-zero)
    const float* W_hh0  = (const float*)d_in[4];
    const float* b_ih0  = (const float*)d_in[5];
    const float* b_hh0  = (const float*)d_in[6];
    const float* W_ih1  = (const float*)d_in[7];
    const float* W_hh1  = (const float*)d_in[8];
    const float* b_ih1  = (const float*)d_in[9];
    const float* b_hh1  = (const float*)d_in[10];
    const float* W_ho   = (const float*)d_in[11];
    const float* b_ho   = (const float*)d_in[12];

    char* ws = (char*)d_ws;
    u32*   hx0  = (u32*)ws;                       //   524,288 B (2 parities, [stamp16|f16])
    u32*   hx1  = (u32*)(ws + 524288);            //   524,288 B
    u32*   posc = (u32*)(ws + 1048576);           //    65,536 B (2 par x 16g x 512 u32)
    // total 1,114,112 B

    // opt into >64KB dynamic LDS (153,088 B: 128KB wfrag + planes + biases)
    hipFuncSetAttribute((const void*)lstm_wave,
                        hipFuncAttributeMaxDynamicSharedMemorySize, 153088);

    zero_ws<<<dim3(128), dim3(256), 0, stream>>>(hx0, 69632);
    lstm_wave<<<dim3(256), dim3(128), 153088, stream>>>(latent, W_lh, b_lh,
                                                        W_hh0, b_ih0, b_hh0,
                                                        W_ih1, W_hh1, b_ih1, b_hh1,
                                                        W_ho, b_ho,
                                                        hx0, hx1, posc,
                                                        (float*)d_out);
}

// Round 15
// 2091.983 us; speedup vs baseline: 3.9091x; 1.0191x over previous
//
#include <hip/hip_runtime.h>
#include <cstdint>

#define TT 512

typedef unsigned short u16;
typedef uint32_t u32;
typedef float    floatx4 __attribute__((ext_vector_type(4)));
typedef _Float16 f16x8   __attribute__((ext_vector_type(8)));
typedef short    short8  __attribute__((ext_vector_type(8)));
typedef u32      u32x4   __attribute__((ext_vector_type(4)));
typedef u32      u32x2   __attribute__((ext_vector_type(2)));

__device__ __forceinline__ float sigm(float x)  { return 1.0f / (1.0f + __expf(-x)); }
__device__ __forceinline__ float tanh_(float x) { return 2.0f / (1.0f + __expf(-2.0f * x)) - 1.0f; }
__device__ __forceinline__ u16 f2h(float f) {           // f32 -> fp16 bits (RNE)
    union { _Float16 h; u16 u; } v; v.h = (_Float16)f; return v.u;
}
#define F16V(p) (*(const f16x8*)(const void*)(p))

// ---- r8 kernel, re-banked (verified 2086us). sc1 stamped-word protocol.
// Session evidence: scope/trip-count/compute/convoy/L2-exchange/own-slice
// lines all closed; dual-group multiplexing (r14) failed with an
// unexplained NaN -> reverted per rigor discipline.
__device__ __forceinline__ void st32_dev(u32* p, u32 v) {
    asm volatile("global_store_dword %0, %1, off sc1" :: "v"(p), "v"(v) : "memory");
}
__device__ __forceinline__ void st64_dev(u32* p, u32 lo, u32 hi) {
    u32x2 d; d[0] = lo; d[1] = hi;
    asm volatile("global_store_dwordx2 %0, %1, off sc1" :: "v"(p), "v"(d) : "memory");
}
__device__ __forceinline__ u32x4 ld128_dev(const u32x4* p) {   // pipelined: no wait
    u32x4 v;
    asm volatile("global_load_dwordx4 %0, %1, off sc1" : "=v"(v) : "v"(p));
    return v;
}
__device__ __forceinline__ u32 ld32_dev(const u32* p) {        // pipelined: no wait
    u32 v;
    asm volatile("global_load_dword %0, %1, off sc1" : "=v"(v) : "v"(p));
    return v;
}
__device__ __forceinline__ void vmcnt0() { asm volatile("s_waitcnt vmcnt(0)" ::: "memory"); }
#define KEEP(x) asm volatile("" : "+v"(x))   // consume-after-wait fence (rule #18)

// zero stamps each launch (stale stamps 1..513 would false-accept).
// hx0 (512KB) + hx1 (512KB) + posc (64KB) contiguous = 69632 dwordx4.
__global__ void zero_ws(u32* base, int n4) {
    u32x4 z = {0u, 0u, 0u, 0u};
    for (int i = blockIdx.x * blockDim.x + threadIdx.x; i < n4; i += gridDim.x * blockDim.x)
        asm volatile("global_store_dwordx4 %0, %1, off sc1"
                     :: "v"(((u32x4*)base) + i), "v"(z) : "memory");
}

#define MFMA_(A_, B_, ACC) ACC = __builtin_amdgcn_mfma_f32_16x16x32_f16(A_, B_, ACC, 0, 0, 0)
#define MS1(ACC, GATE_) { f16x8 A_ = F16V(fs0 + (GATE_) * 4096); MFMA_(A_, Bh, ACC); }
#define MS3(ACC, GATE_) { f16x8 A1_ = F16V(fs1 + (GATE_) * 4096); MFMA_(A1_, Bh, ACC); \
    f16x8 A2_ = F16V(fs2 + (GATE_) * 4096); MFMA_(A2_, Ch, ACC); }

#define GATE0(R) { \
    const int d_ = dg16 + 4 * q + (R); \
    float zi_ = Zi[R] + bs[0][d_], zf_ = Zf[R] + bs[1][d_]; \
    float zg_ = Zg[R] + bs[2][d_], zo_ = Zo[R] + bs[3][d_]; \
    float c_  = sigm(zf_) * cv[R] + sigm(zi_) * tanh_(zg_); cv[R] = c_; \
    float hv_ = sigm(zo_) * tanh_(c_); \
    st32_dev(&hx0w[d_ * 16 + bq], tgthi | (u32)f2h(hv_)); }
#define GATE1(R) { \
    const int d_ = dg16 + 4 * q + (R); \
    float zi_ = Yi[R] + bs[0][d_], zf_ = Yf[R] + bs[1][d_]; \
    float zg_ = Yg[R] + bs[2][d_], zo_ = Yo[R] + bs[3][d_]; \
    float c_  = sigm(zf_) * cv[R] + sigm(zi_) * tanh_(zg_); cv[R] = c_; \
    float hv_ = sigm(zo_) * tanh_(c_); \
    st32_dev(&hx1w[d_ * 16 + bq], tgthi | (u32)f2h(hv_)); \
    part += hv_ * who_s[d_]; }

#define UNPACK0(v, i4) { const int d_ = (i4) >> 2, bb_ = ((i4) & 3) * 4; \
    h0f[bb_ + 0][d_] = (u16)((v)[0] & 0xFFFFu); \
    h0f[bb_ + 1][d_] = (u16)((v)[1] & 0xFFFFu); \
    h0f[bb_ + 2][d_] = (u16)((v)[2] & 0xFFFFu); \
    h0f[bb_ + 3][d_] = (u16)((v)[3] & 0xFFFFu); }
#define UNPACK1(v, i4) { const int d_ = (i4) >> 2, bb_ = ((i4) & 3) * 4; \
    h1f[bb_ + 0][d_] = (u16)((v)[0] & 0xFFFFu); \
    h1f[bb_ + 1][d_] = (u16)((v)[1] & 0xFFFFu); \
    h1f[bb_ + 2][d_] = (u16)((v)[2] & 0xFFFFu); \
    h1f[bb_ + 3][d_] = (u16)((v)[3] & 0xFFFFu); }
#define STALE4(v) (((v)[0] ^ tgthi) | ((v)[1] ^ tgthi) | ((v)[2] ^ tgthi) | ((v)[3] ^ tgthi))

// 256 blocks = 16 groups x (8 L0-slices + 8 L1-slices), 128 threads, 1/CU.
// Weights LDS-resident: L0 64KB (W_hh0 slice), L1 128KB (W_ih1+W_hh1 slice).
__launch_bounds__(128, 1)
__global__ void lstm_wave(const float* __restrict__ latent, const float* __restrict__ W_lh,
                          const float* __restrict__ b_lh,
                          const float* __restrict__ W_hh0,
                          const float* __restrict__ b_ih0, const float* __restrict__ b_hh0,
                          const float* __restrict__ W_ih1, const float* __restrict__ W_hh1,
                          const float* __restrict__ b_ih1, const float* __restrict__ b_hh1,
                          const float* __restrict__ W_ho,  const float* __restrict__ b_ho,
                          u32* __restrict__ hx0, u32* __restrict__ hx1,
                          u32* __restrict__ posc, float* __restrict__ out)
{
    extern __shared__ __align__(16) char smem[];
    short* wlds     = (short*)smem;                          // <=128KB weight frags
    u16 (*h0f)[264] = (u16(*)[264])(smem + 131072);          // 8448 B
    u16 (*h1f)[264] = (u16(*)[264])(smem + 139520);          // 8448 B (L1 only)
    float (*bs)[256] = (float(*)[256])(smem + 147968);       // 4096 B (b0 or b1)
    float* who_s    = (float*)(smem + 152064);               // 1024 B (L1 only)

    const int tid  = threadIdx.x;      // 128 threads, 2 waves
    const int w    = tid >> 6;
    const int lane = tid & 63;
    const int bq   = lane & 15;
    const int q    = lane >> 4;
    const int g    = blockIdx.x & 15;  // batch group
    const int s16  = blockIdx.x >> 4;  // 0..15
    const int role = s16 >> 3;         // 0 = layer-0 block, 1 = layer-1 block
    const int jl   = s16 & 7;          // 32-dim slice within the layer
    const int bglo = g * 16;

    // ---- stage this block's weight slice f32->f16 into LDS (one-time)
    {
        const int nv = role ? 8192 : 4096;       // 8-float vectors
        for (int i = tid; i < nv; i += 128) {
            const int l8 = i & 63, s8 = (i >> 6) & 7, gate8 = (i >> 9) & 3;
            const int dgl = (i >> 11) & 1, G = (i >> 12) & 1;
            const float* W = role ? (G ? W_hh1 : W_ih1) : W_hh0;
            const int rowdim = jl * 32 + dgl * 16 + (l8 & 15);
            const float* src = W + (gate8 * 256 + rowdim) * 256 + s8 * 32 + (l8 >> 4) * 8;
            short8 v;
#pragma unroll
            for (int jj = 0; jj < 8; ++jj) v[jj] = (short)f2h(src[jj]);
            *(short8*)(wlds + l8 * 8 + s8 * 512 + gate8 * 4096 + dgl * 16384 + G * 32768) = v;
        }
    }
    for (int i = tid; i < 1024; i += 128)
        bs[i >> 8][i & 255] = role ? (b_ih1[i] + b_hh1[i]) : (b_ih0[i] + b_hh0[i]);
    if (role) { who_s[tid] = W_ho[tid]; who_s[tid + 128] = W_ho[tid + 128]; }

    // ---- h_init = latent @ W_lh.T + b_lh (fp32), rounded to fp16
    {
        const int b = tid >> 3, d0 = (tid & 7) * 32;
        const float* lr = latent + (bglo + b) * 128;
        for (int jj = 0; jj < 32; ++jj) {
            const int d = d0 + jj;
            const float* wr = W_lh + d * 128;
            float acc = b_lh[d];
            for (int c = 0; c < 128; c += 4) {
                float4 lv = *(const float4*)(lr + c);
                float4 wv = *(const float4*)(wr + c);
                acc += lv.x * wv.x + lv.y * wv.y + lv.z * wv.z + lv.w * wv.w;
            }
            u16 hb = f2h(acc);
            h0f[b][d] = hb;
            if (role) h1f[b][d] = hb;
        }
    }
    __syncthreads();

    const int dg16 = jl * 32 + w * 16;
    const short* fbA = wlds + w * 16384 + (size_t)lane * 8;  // L0: W_hh0; L1: W_ih1
    float cv[4] = {0.f, 0.f, 0.f, 0.f};
    const float bho = b_ho[0];
    const unsigned long long ALL = 0xFFFFFFFFFFFFFFFFull;

    if (role == 0) {
        // ================= layer-0 block: phases 0..TT-1 =================
        for (int p = 0; p < TT; ++p) {
            const int pb = p & 1;
            u32* hx0w = hx0 + pb * 65536 + g * 4096;
            const u32* hx1w = hx1 + pb * 65536 + g * 4096;
            const u32 tgthi = (u32)(p + 1) << 16;
            const u32 tgt32 = (u32)(p + 1);

            floatx4 Zi = {0.f,0.f,0.f,0.f}, Zf = {0.f,0.f,0.f,0.f};
            floatx4 Zg = {0.f,0.f,0.f,0.f}, Zo = {0.f,0.f,0.f,0.f};
#pragma unroll
            for (int s = 0; s < 8; ++s) {
                f16x8 Bh = F16V(&h0f[bq][s * 32 + q * 8]);
                const short* fs0 = fbA + s * 512;
                MS1(Zi, 0) MS1(Zf, 1) MS1(Zg, 2) MS1(Zo, 3)
            }
            GATE0(0) GATE0(1) GATE0(2) GATE0(3)
            if (p == TT - 1) break;          // final store issued; nothing more needed

            // readback h0(p+1) + lockstep pacing sample of L1 progress
            u32x4 va0, va1, va2, va3, va4, va5, va6, va7;
            u32 pc = 0;
            const u32x4* s4a = (const u32x4*)hx0w;
#define ISSUE0() do { \
            va0 = ld128_dev(s4a + tid);       va1 = ld128_dev(s4a + tid + 128); \
            va2 = ld128_dev(s4a + tid + 256); va3 = ld128_dev(s4a + tid + 384); \
            va4 = ld128_dev(s4a + tid + 512); va5 = ld128_dev(s4a + tid + 640); \
            va6 = ld128_dev(s4a + tid + 768); va7 = ld128_dev(s4a + tid + 896); \
            if ((lane < 8) && p) pc = ld32_dev(hx1w + lane * 512); \
        } while (0)
            ISSUE0();
            __syncthreads();                 // both waves done reading h0f
            int it = 0;
            while (true) {
                vmcnt0();
                KEEP(va0); KEEP(va1); KEEP(va2); KEEP(va3);
                KEEP(va4); KEEP(va5); KEEP(va6); KEEP(va7); KEEP(pc);
                u32 sh = STALE4(va0) | STALE4(va1) | STALE4(va2) | STALE4(va3)
                       | STALE4(va4) | STALE4(va5) | STALE4(va6) | STALE4(va7);
                const bool okp = ((lane < 8) && p) ? ((pc >> 16) >= tgt32) : true;
                const bool ok = ((sh & 0xFFFF0000u) == 0u) && okp;
                if (__ballot(ok) == ALL) break;
                if (++it > 20000) break;     // finite-wrong, never hang
                ISSUE0();
            }
#undef ISSUE0
            UNPACK0(va0, tid);       UNPACK0(va1, tid + 128);
            UNPACK0(va2, tid + 256); UNPACK0(va3, tid + 384);
            UNPACK0(va4, tid + 512); UNPACK0(va5, tid + 640);
            UNPACK0(va6, tid + 768); UNPACK0(va7, tid + 896);
            __syncthreads();                 // h0f ready for next phase
        }
    } else {
        // ================= layer-1 block: phases 0..TT =================
        const short* fbB = fbA;              // fs2 = fs1 + 32768 handles W_hh1
        const bool isout = (jl == 0);
        for (int p = 0; p <= TT; ++p) {
            const int pb = p & 1;
            const u32* hx0w = hx0 + pb * 65536 + g * 4096;
            u32* hx1w = hx1 + pb * 65536 + g * 4096;
            u32* poscw = posc + (pb * 16 + g) * 512;
            const u32 tgthi = (u32)(p + 1) << 16;
            const u32 tgt32 = (u32)(p + 1);

            if (p >= 1) {
                floatx4 Yi = {0.f,0.f,0.f,0.f}, Yf = {0.f,0.f,0.f,0.f};
                floatx4 Yg = {0.f,0.f,0.f,0.f}, Yo = {0.f,0.f,0.f,0.f};
#pragma unroll
                for (int s = 0; s < 8; ++s) {
                    f16x8 Bh = F16V(&h0f[bq][s * 32 + q * 8]);
                    f16x8 Ch = F16V(&h1f[bq][s * 32 + q * 8]);
                    const short* fs1 = fbB + s * 512;
                    const short* fs2 = fs1 + 32768;
                    MS3(Yi, 0) MS3(Yf, 1) MS3(Yg, 2) MS3(Yo, 3)
                }
                float part = 0.0f;
                GATE1(0) GATE1(1) GATE1(2) GATE1(3)
                part += __shfl_xor(part, 16, 64);
                part += __shfl_xor(part, 32, 64);
                if (q == 0)
                    st64_dev(poscw + (bq * 16 + jl * 2 + w) * 2,
                             __float_as_uint(part), tgt32);
            }

            const bool rdA = p < TT;
            const bool rdB = (p >= 1) && (p < TT);
            const bool rdP = isout && (p >= 1) && (tid < 16);
            u32x4 va0, va1, va2, va3, va4, va5, va6, va7;
            u32x4 vb0, vb1, vb2, vb3, vb4, vb5, vb6, vb7;
            u32x4 po0, po1, po2, po3, po4, po5, po6, po7;
            const u32x4* s4a = (const u32x4*)hx0w;
            const u32x4* s4b = (const u32x4*)hx1w;
            const u32x4* s4p = (const u32x4*)poscw + tid * 8;
#define ISSUE1() do { \
            if (rdA) { \
                va0 = ld128_dev(s4a + tid);       va1 = ld128_dev(s4a + tid + 128); \
                va2 = ld128_dev(s4a + tid + 256); va3 = ld128_dev(s4a + tid + 384); \
                va4 = ld128_dev(s4a + tid + 512); va5 = ld128_dev(s4a + tid + 640); \
                va6 = ld128_dev(s4a + tid + 768); va7 = ld128_dev(s4a + tid + 896); } \
            if (rdB) { \
                vb0 = ld128_dev(s4b + tid);       vb1 = ld128_dev(s4b + tid + 128); \
                vb2 = ld128_dev(s4b + tid + 256); vb3 = ld128_dev(s4b + tid + 384); \
                vb4 = ld128_dev(s4b + tid + 512); vb5 = ld128_dev(s4b + tid + 640); \
                vb6 = ld128_dev(s4b + tid + 768); vb7 = ld128_dev(s4b + tid + 896); } \
            if (rdP) { \
                po0 = ld128_dev(s4p);     po1 = ld128_dev(s4p + 1); \
                po2 = ld128_dev(s4p + 2); po3 = ld128_dev(s4p + 3); \
                po4 = ld128_dev(s4p + 4); po5 = ld128_dev(s4p + 5); \
                po6 = ld128_dev(s4p + 6); po7 = ld128_dev(s4p + 7); } \
        } while (0)
            ISSUE1();
            __syncthreads();                 // both waves done reading h0f/h1f
            int it = 0;
            while (true) {
                vmcnt0();
                u32 sh = 0, sf = 0;
                if (rdA) {
                    KEEP(va0); KEEP(va1); KEEP(va2); KEEP(va3);
                    KEEP(va4); KEEP(va5); KEEP(va6); KEEP(va7);
                    sh |= STALE4(va0) | STALE4(va1) | STALE4(va2) | STALE4(va3)
                        | STALE4(va4) | STALE4(va5) | STALE4(va6) | STALE4(va7);
                }
                if (rdB) {
                    KEEP(vb0); KEEP(vb1); KEEP(vb2); KEEP(vb3);
                    KEEP(vb4); KEEP(vb5); KEEP(vb6); KEEP(vb7);
                    sh |= STALE4(vb0) | STALE4(vb1) | STALE4(vb2) | STALE4(vb3)
                        | STALE4(vb4) | STALE4(vb5) | STALE4(vb6) | STALE4(vb7);
                }
                if (rdP) {
                    KEEP(po0); KEEP(po1); KEEP(po2); KEEP(po3);
                    KEEP(po4); KEEP(po5); KEEP(po6); KEEP(po7);
                    sf |= (po0[1] ^ tgt32) | (po0[3] ^ tgt32) | (po1[1] ^ tgt32) | (po1[3] ^ tgt32)
                        | (po2[1] ^ tgt32) | (po2[3] ^ tgt32) | (po3[1] ^ tgt32) | (po3[3] ^ tgt32)
                        | (po4[1] ^ tgt32) | (po4[3] ^ tgt32) | (po5[1] ^ tgt32) | (po5[3] ^ tgt32)
                        | (po6[1] ^ tgt32) | (po6[3] ^ tgt32) | (po7[1] ^ tgt32) | (po7[3] ^ tgt32);
                }
                const bool ok = ((sh & 0xFFFF0000u) == 0u) && (sf == 0u);
                if (__ballot(ok) == ALL) break;
                if (++it > 20000) break;     // finite-wrong, never hang
                ISSUE1();
            }
#undef ISSUE1
            if (rdA) {
                UNPACK0(va0, tid);       UNPACK0(va1, tid + 128);
                UNPACK0(va2, tid + 256); UNPACK0(va3, tid + 384);
                UNPACK0(va4, tid + 512); UNPACK0(va5, tid + 640);
                UNPACK0(va6, tid + 768); UNPACK0(va7, tid + 896);
            }
            if (rdB) {
                UNPACK1(vb0, tid);       UNPACK1(vb1, tid + 128);
                UNPACK1(vb2, tid + 256); UNPACK1(vb3, tid + 384);
                UNPACK1(vb4, tid + 512); UNPACK1(vb5, tid + 640);
                UNPACK1(vb6, tid + 768); UNPACK1(vb7, tid + 896);
            }
            if (rdP) {                       // assemble out[t = p-1]
                float o = bho;
                o += __uint_as_float(po0[0]) + __uint_as_float(po0[2]);
                o += __uint_as_float(po1[0]) + __uint_as_float(po1[2]);
                o += __uint_as_float(po2[0]) + __uint_as_float(po2[2]);
                o += __uint_as_float(po3[0]) + __uint_as_float(po3[2]);
                o += __uint_as_float(po4[0]) + __uint_as_float(po4[2]);
                o += __uint_as_float(po5[0]) + __uint_as_float(po5[2]);
                o += __uint_as_float(po6[0]) + __uint_as_float(po6[2]);
                o += __uint_as_float(po7[0]) + __uint_as_float(po7[2]);
                out[(bglo + tid) * TT + (p - 1)] = o;
            }
            __syncthreads();                 // LDS planes ready for next phase
        }
    }
}

extern "C" void kernel_launch(void* const* d_in, const int* in_sizes, int n_in,
                              void* d_out, int out_size, void* d_ws, size_t ws_size,
                              hipStream_t stream)
{
    const float* latent = (const float*)d_in[0];
    const float* W_lh   = (const float*)d_in[1];
    const float* b_lh   = (const float*)d_in[2];
    // d_in[3] = W_ih0: unused (layer-0 inputs are all-zero)
    const float* W_hh0  = (const float*)d_in[4];
    const float* b_ih0  = (const float*)d_in[5];
    const float* b_hh0  = (const float*)d_in[6];
    const float* W_ih1  = (const float*)d_in[7];
    const float* W_hh1  = (const float*)d_in[8];
    const float* b_ih1  = (const float*)d_in[9];
    const float* b_hh1  = (const float*)d_in[10];
    const float* W_ho   = (const float*)d_in[11];
    const float* b_ho   = (const float*)d_in[12];

    char* ws = (char*)d_ws;
    u32*   hx0  = (u32*)ws;                       //   524,288 B (2 parities, [stamp16|f16])
    u32*   hx1  = (u32*)(ws + 524288);            //   524,288 B
    u32*   posc = (u32*)(ws + 1048576);           //    65,536 B (2 par x 16g x 512 u32)
    // total 1,114,112 B

    // opt into >64KB dynamic LDS (153,088 B: 128KB wfrag + planes + biases)
    hipFuncSetAttribute((const void*)lstm_wave,
                        hipFuncAttributeMaxDynamicSharedMemorySize, 153088);

    zero_ws<<<dim3(128), dim3(256), 0, stream>>>(hx0, 69632);
    lstm_wave<<<dim3(256), dim3(128), 153088, stream>>>(latent, W_lh, b_lh,
                                                        W_hh0, b_ih0, b_hh0,
                                                        W_ih1, W_hh1, b_ih1, b_hh1,
                                                        W_ho, b_ho,
                                                        hx0, hx1, posc,
                                                        (float*)d_out);
}

// Round 17
// 1998.703 us; speedup vs baseline: 4.0915x; 1.0467x over previous
//
#include <hip/hip_runtime.h>
#include <cstdint>

#define TT 512

typedef unsigned short u16;
typedef uint32_t u32;
typedef float    floatx4 __attribute__((ext_vector_type(4)));
typedef _Float16 f16x8   __attribute__((ext_vector_type(8)));
typedef short    short8  __attribute__((ext_vector_type(8)));
typedef u32      u32x4   __attribute__((ext_vector_type(4)));
typedef u32      u32x2   __attribute__((ext_vector_type(2)));

__device__ __forceinline__ float sigm(float x)  { return 1.0f / (1.0f + __expf(-x)); }
__device__ __forceinline__ float tanh_(float x) { return 2.0f / (1.0f + __expf(-2.0f * x)) - 1.0f; }
__device__ __forceinline__ u16 f2h(float f) {           // f32 -> fp16 bits (RNE)
    union { _Float16 h; u16 u; } v; v.h = (_Float16)f; return v.u;
}
#define F16V(p) (*(const f16x8*)(const void*)(p))

// ---- r8 kernel + first-attempt aging (resubmit: r16 was an infra failure,
// kernel never ran). sc1 stamped-word protocol; scope/trip/compute/convoy/
// L2-exchange lines all closed r1-r12.
// Timing fix: readback loads were issued at the same barrier where partners'
// stores depart -> attempt-1 always snapshots stale data at the MALL and the
// retry costs a full extra RT. Now: barrier -> ~0.35us sleep -> issue ->
// check. Stores land ~0.4-0.5us after compute end; loads serviced ~0.8-1.1us
// -> attempt-1 fresh. Bounded downside if late: one retry, same as before.
__device__ __forceinline__ void st32_dev(u32* p, u32 v) {
    asm volatile("global_store_dword %0, %1, off sc1" :: "v"(p), "v"(v) : "memory");
}
__device__ __forceinline__ void st64_dev(u32* p, u32 lo, u32 hi) {
    u32x2 d; d[0] = lo; d[1] = hi;
    asm volatile("global_store_dwordx2 %0, %1, off sc1" :: "v"(p), "v"(d) : "memory");
}
__device__ __forceinline__ u32x4 ld128_dev(const u32x4* p) {   // pipelined: no wait
    u32x4 v;
    asm volatile("global_load_dwordx4 %0, %1, off sc1" : "=v"(v) : "v"(p));
    return v;
}
__device__ __forceinline__ u32 ld32_dev(const u32* p) {        // pipelined: no wait
    u32 v;
    asm volatile("global_load_dword %0, %1, off sc1" : "=v"(v) : "v"(p));
    return v;
}
__device__ __forceinline__ void vmcnt0() { asm volatile("s_waitcnt vmcnt(0)" ::: "memory"); }
#define KEEP(x) asm volatile("" : "+v"(x))   // consume-after-wait fence (rule #18)
// ~0.35us @ ~2.1GHz: 6 x s_sleep(2) = 6 x 128 cyc = 768 cyc
__device__ __forceinline__ void age_sleep() {
#pragma unroll
    for (int z = 0; z < 6; ++z) __builtin_amdgcn_s_sleep(2);
}

// zero stamps each launch (stale stamps 1..513 would false-accept).
// hx0 (512KB) + hx1 (512KB) + posc (64KB) contiguous = 69632 dwordx4.
__global__ void zero_ws(u32* base, int n4) {
    u32x4 z = {0u, 0u, 0u, 0u};
    for (int i = blockIdx.x * blockDim.x + threadIdx.x; i < n4; i += gridDim.x * blockDim.x)
        asm volatile("global_store_dwordx4 %0, %1, off sc1"
                     :: "v"(((u32x4*)base) + i), "v"(z) : "memory");
}

#define MFMA_(A_, B_, ACC) ACC = __builtin_amdgcn_mfma_f32_16x16x32_f16(A_, B_, ACC, 0, 0, 0)
#define MS1(ACC, GATE_) { f16x8 A_ = F16V(fs0 + (GATE_) * 4096); MFMA_(A_, Bh, ACC); }
#define MS3(ACC, GATE_) { f16x8 A1_ = F16V(fs1 + (GATE_) * 4096); MFMA_(A1_, Bh, ACC); \
    f16x8 A2_ = F16V(fs2 + (GATE_) * 4096); MFMA_(A2_, Ch, ACC); }

#define GATE0(R) { \
    const int d_ = dg16 + 4 * q + (R); \
    float zi_ = Zi[R] + bs[0][d_], zf_ = Zf[R] + bs[1][d_]; \
    float zg_ = Zg[R] + bs[2][d_], zo_ = Zo[R] + bs[3][d_]; \
    float c_  = sigm(zf_) * cv[R] + sigm(zi_) * tanh_(zg_); cv[R] = c_; \
    float hv_ = sigm(zo_) * tanh_(c_); \
    st32_dev(&hx0w[d_ * 16 + bq], tgthi | (u32)f2h(hv_)); }
#define GATE1(R) { \
    const int d_ = dg16 + 4 * q + (R); \
    float zi_ = Yi[R] + bs[0][d_], zf_ = Yf[R] + bs[1][d_]; \
    float zg_ = Yg[R] + bs[2][d_], zo_ = Yo[R] + bs[3][d_]; \
    float c_  = sigm(zf_) * cv[R] + sigm(zi_) * tanh_(zg_); cv[R] = c_; \
    float hv_ = sigm(zo_) * tanh_(c_); \
    st32_dev(&hx1w[d_ * 16 + bq], tgthi | (u32)f2h(hv_)); \
    part += hv_ * who_s[d_]; }

#define UNPACK0(v, i4) { const int d_ = (i4) >> 2, bb_ = ((i4) & 3) * 4; \
    h0f[bb_ + 0][d_] = (u16)((v)[0] & 0xFFFFu); \
    h0f[bb_ + 1][d_] = (u16)((v)[1] & 0xFFFFu); \
    h0f[bb_ + 2][d_] = (u16)((v)[2] & 0xFFFFu); \
    h0f[bb_ + 3][d_] = (u16)((v)[3] & 0xFFFFu); }
#define UNPACK1(v, i4) { const int d_ = (i4) >> 2, bb_ = ((i4) & 3) * 4; \
    h1f[bb_ + 0][d_] = (u16)((v)[0] & 0xFFFFu); \
    h1f[bb_ + 1][d_] = (u16)((v)[1] & 0xFFFFu); \
    h1f[bb_ + 2][d_] = (u16)((v)[2] & 0xFFFFu); \
    h1f[bb_ + 3][d_] = (u16)((v)[3] & 0xFFFFu); }
#define STALE4(v) (((v)[0] ^ tgthi) | ((v)[1] ^ tgthi) | ((v)[2] ^ tgthi) | ((v)[3] ^ tgthi))

// 256 blocks = 16 groups x (8 L0-slices + 8 L1-slices), 128 threads, 1/CU.
// Weights LDS-resident: L0 64KB (W_hh0 slice), L1 128KB (W_ih1+W_hh1 slice).
__launch_bounds__(128, 1)
__global__ void lstm_wave(const float* __restrict__ latent, const float* __restrict__ W_lh,
                          const float* __restrict__ b_lh,
                          const float* __restrict__ W_hh0,
                          const float* __restrict__ b_ih0, const float* __restrict__ b_hh0,
                          const float* __restrict__ W_ih1, const float* __restrict__ W_hh1,
                          const float* __restrict__ b_ih1, const float* __restrict__ b_hh1,
                          const float* __restrict__ W_ho,  const float* __restrict__ b_ho,
                          u32* __restrict__ hx0, u32* __restrict__ hx1,
                          u32* __restrict__ posc, float* __restrict__ out)
{
    extern __shared__ __align__(16) char smem[];
    short* wlds     = (short*)smem;                          // <=128KB weight frags
    u16 (*h0f)[264] = (u16(*)[264])(smem + 131072);          // 8448 B
    u16 (*h1f)[264] = (u16(*)[264])(smem + 139520);          // 8448 B (L1 only)
    float (*bs)[256] = (float(*)[256])(smem + 147968);       // 4096 B (b0 or b1)
    float* who_s    = (float*)(smem + 152064);               // 1024 B (L1 only)

    const int tid  = threadIdx.x;      // 128 threads, 2 waves
    const int w    = tid >> 6;
    const int lane = tid & 63;
    const int bq   = lane & 15;
    const int q    = lane >> 4;
    const int g    = blockIdx.x & 15;  // batch group
    const int s16  = blockIdx.x >> 4;  // 0..15
    const int role = s16 >> 3;         // 0 = layer-0 block, 1 = layer-1 block
    const int jl   = s16 & 7;          // 32-dim slice within the layer
    const int bglo = g * 16;

    // ---- stage this block's weight slice f32->f16 into LDS (one-time)
    {
        const int nv = role ? 8192 : 4096;       // 8-float vectors
        for (int i = tid; i < nv; i += 128) {
            const int l8 = i & 63, s8 = (i >> 6) & 7, gate8 = (i >> 9) & 3;
            const int dgl = (i >> 11) & 1, G = (i >> 12) & 1;
            const float* W = role ? (G ? W_hh1 : W_ih1) : W_hh0;
            const int rowdim = jl * 32 + dgl * 16 + (l8 & 15);
            const float* src = W + (gate8 * 256 + rowdim) * 256 + s8 * 32 + (l8 >> 4) * 8;
            short8 v;
#pragma unroll
            for (int jj = 0; jj < 8; ++jj) v[jj] = (short)f2h(src[jj]);
            *(short8*)(wlds + l8 * 8 + s8 * 512 + gate8 * 4096 + dgl * 16384 + G * 32768) = v;
        }
    }
    for (int i = tid; i < 1024; i += 128)
        bs[i >> 8][i & 255] = role ? (b_ih1[i] + b_hh1[i]) : (b_ih0[i] + b_hh0[i]);
    if (role) { who_s[tid] = W_ho[tid]; who_s[tid + 128] = W_ho[tid + 128]; }

    // ---- h_init = latent @ W_lh.T + b_lh (fp32), rounded to fp16
    {
        const int b = tid >> 3, d0 = (tid & 7) * 32;
        const float* lr = latent + (bglo + b) * 128;
        for (int jj = 0; jj < 32; ++jj) {
            const int d = d0 + jj;
            const float* wr = W_lh + d * 128;
            float acc = b_lh[d];
            for (int c = 0; c < 128; c += 4) {
                float4 lv = *(const float4*)(lr + c);
                float4 wv = *(const float4*)(wr + c);
                acc += lv.x * wv.x + lv.y * wv.y + lv.z * wv.z + lv.w * wv.w;
            }
            u16 hb = f2h(acc);
            h0f[b][d] = hb;
            if (role) h1f[b][d] = hb;
        }
    }
    __syncthreads();

    const int dg16 = jl * 32 + w * 16;
    const short* fbA = wlds + w * 16384 + (size_t)lane * 8;  // L0: W_hh0; L1: W_ih1
    float cv[4] = {0.f, 0.f, 0.f, 0.f};
    const float bho = b_ho[0];
    const unsigned long long ALL = 0xFFFFFFFFFFFFFFFFull;

    if (role == 0) {
        // ================= layer-0 block: phases 0..TT-1 =================
        for (int p = 0; p < TT; ++p) {
            const int pb = p & 1;
            u32* hx0w = hx0 + pb * 65536 + g * 4096;
            const u32* hx1w = hx1 + pb * 65536 + g * 4096;
            const u32 tgthi = (u32)(p + 1) << 16;
            const u32 tgt32 = (u32)(p + 1);

            floatx4 Zi = {0.f,0.f,0.f,0.f}, Zf = {0.f,0.f,0.f,0.f};
            floatx4 Zg = {0.f,0.f,0.f,0.f}, Zo = {0.f,0.f,0.f,0.f};
#pragma unroll
            for (int s = 0; s < 8; ++s) {
                f16x8 Bh = F16V(&h0f[bq][s * 32 + q * 8]);
                const short* fs0 = fbA + s * 512;
                MS1(Zi, 0) MS1(Zf, 1) MS1(Zg, 2) MS1(Zo, 3)
            }
            GATE0(0) GATE0(1) GATE0(2) GATE0(3)
            if (p == TT - 1) break;          // final store issued; nothing more needed

            // readback h0(p+1) + lockstep pacing sample of L1 progress.
            // barrier FIRST, then age ~0.35us, then issue -> fresh attempt-1.
            u32x4 va0, va1, va2, va3, va4, va5, va6, va7;
            u32 pc = 0;
            const u32x4* s4a = (const u32x4*)hx0w;
#define ISSUE0() do { \
            va0 = ld128_dev(s4a + tid);       va1 = ld128_dev(s4a + tid + 128); \
            va2 = ld128_dev(s4a + tid + 256); va3 = ld128_dev(s4a + tid + 384); \
            va4 = ld128_dev(s4a + tid + 512); va5 = ld128_dev(s4a + tid + 640); \
            va6 = ld128_dev(s4a + tid + 768); va7 = ld128_dev(s4a + tid + 896); \
            if ((lane < 8) && p) pc = ld32_dev(hx1w + lane * 512); \
        } while (0)
            __syncthreads();                 // both waves done reading h0f
            age_sleep();
            ISSUE0();
            int it = 0;
            while (true) {
                vmcnt0();
                KEEP(va0); KEEP(va1); KEEP(va2); KEEP(va3);
                KEEP(va4); KEEP(va5); KEEP(va6); KEEP(va7); KEEP(pc);
                u32 sh = STALE4(va0) | STALE4(va1) | STALE4(va2) | STALE4(va3)
                       | STALE4(va4) | STALE4(va5) | STALE4(va6) | STALE4(va7);
                const bool okp = ((lane < 8) && p) ? ((pc >> 16) >= tgt32) : true;
                const bool ok = ((sh & 0xFFFF0000u) == 0u) && okp;
                if (__ballot(ok) == ALL) break;
                if (++it > 20000) break;     // finite-wrong, never hang
                ISSUE0();
            }
#undef ISSUE0
            UNPACK0(va0, tid);       UNPACK0(va1, tid + 128);
            UNPACK0(va2, tid + 256); UNPACK0(va3, tid + 384);
            UNPACK0(va4, tid + 512); UNPACK0(va5, tid + 640);
            UNPACK0(va6, tid + 768); UNPACK0(va7, tid + 896);
            __syncthreads();                 // h0f ready for next phase
        }
    } else {
        // ================= layer-1 block: phases 0..TT =================
        const short* fbB = fbA;              // fs2 = fs1 + 32768 handles W_hh1
        const bool isout = (jl == 0);
        for (int p = 0; p <= TT; ++p) {
            const int pb = p & 1;
            const u32* hx0w = hx0 + pb * 65536 + g * 4096;
            u32* hx1w = hx1 + pb * 65536 + g * 4096;
            u32* poscw = posc + (pb * 16 + g) * 512;
            const u32 tgthi = (u32)(p + 1) << 16;
            const u32 tgt32 = (u32)(p + 1);

            if (p >= 1) {
                floatx4 Yi = {0.f,0.f,0.f,0.f}, Yf = {0.f,0.f,0.f,0.f};
                floatx4 Yg = {0.f,0.f,0.f,0.f}, Yo = {0.f,0.f,0.f,0.f};
#pragma unroll
                for (int s = 0; s < 8; ++s) {
                    f16x8 Bh = F16V(&h0f[bq][s * 32 + q * 8]);
                    f16x8 Ch = F16V(&h1f[bq][s * 32 + q * 8]);
                    const short* fs1 = fbB + s * 512;
                    const short* fs2 = fs1 + 32768;
                    MS3(Yi, 0) MS3(Yf, 1) MS3(Yg, 2) MS3(Yo, 3)
                }
                float part = 0.0f;
                GATE1(0) GATE1(1) GATE1(2) GATE1(3)
                part += __shfl_xor(part, 16, 64);
                part += __shfl_xor(part, 32, 64);
                if (q == 0)
                    st64_dev(poscw + (bq * 16 + jl * 2 + w) * 2,
                             __float_as_uint(part), tgt32);
            }

            const bool rdA = p < TT;
            const bool rdB = (p >= 1) && (p < TT);
            const bool rdP = isout && (p >= 1) && (tid < 16);
            u32x4 va0, va1, va2, va3, va4, va5, va6, va7;
            u32x4 vb0, vb1, vb2, vb3, vb4, vb5, vb6, vb7;
            u32x4 po0, po1, po2, po3, po4, po5, po6, po7;
            const u32x4* s4a = (const u32x4*)hx0w;
            const u32x4* s4b = (const u32x4*)hx1w;
            const u32x4* s4p = (const u32x4*)poscw + tid * 8;
#define ISSUE1() do { \
            if (rdA) { \
                va0 = ld128_dev(s4a + tid);       va1 = ld128_dev(s4a + tid + 128); \
                va2 = ld128_dev(s4a + tid + 256); va3 = ld128_dev(s4a + tid + 384); \
                va4 = ld128_dev(s4a + tid + 512); va5 = ld128_dev(s4a + tid + 640); \
                va6 = ld128_dev(s4a + tid + 768); va7 = ld128_dev(s4a + tid + 896); } \
            if (rdB) { \
                vb0 = ld128_dev(s4b + tid);       vb1 = ld128_dev(s4b + tid + 128); \
                vb2 = ld128_dev(s4b + tid + 256); vb3 = ld128_dev(s4b + tid + 384); \
                vb4 = ld128_dev(s4b + tid + 512); vb5 = ld128_dev(s4b + tid + 640); \
                vb6 = ld128_dev(s4b + tid + 768); vb7 = ld128_dev(s4b + tid + 896); } \
            if (rdP) { \
                po0 = ld128_dev(s4p);     po1 = ld128_dev(s4p + 1); \
                po2 = ld128_dev(s4p + 2); po3 = ld128_dev(s4p + 3); \
                po4 = ld128_dev(s4p + 4); po5 = ld128_dev(s4p + 5); \
                po6 = ld128_dev(s4p + 6); po7 = ld128_dev(s4p + 7); } \
        } while (0)
            __syncthreads();                 // both waves done reading h0f/h1f
            age_sleep();
            ISSUE1();
            int it = 0;
            while (true) {
                vmcnt0();
                u32 sh = 0, sf = 0;
                if (rdA) {
                    KEEP(va0); KEEP(va1); KEEP(va2); KEEP(va3);
                    KEEP(va4); KEEP(va5); KEEP(va6); KEEP(va7);
                    sh |= STALE4(va0) | STALE4(va1) | STALE4(va2) | STALE4(va3)
                        | STALE4(va4) | STALE4(va5) | STALE4(va6) | STALE4(va7);
                }
                if (rdB) {
                    KEEP(vb0); KEEP(vb1); KEEP(vb2); KEEP(vb3);
                    KEEP(vb4); KEEP(vb5); KEEP(vb6); KEEP(vb7);
                    sh |= STALE4(vb0) | STALE4(vb1) | STALE4(vb2) | STALE4(vb3)
                        | STALE4(vb4) | STALE4(vb5) | STALE4(vb6) | STALE4(vb7);
                }
                if (rdP) {
                    KEEP(po0); KEEP(po1); KEEP(po2); KEEP(po3);
                    KEEP(po4); KEEP(po5); KEEP(po6); KEEP(po7);
                    sf |= (po0[1] ^ tgt32) | (po0[3] ^ tgt32) | (po1[1] ^ tgt32) | (po1[3] ^ tgt32)
                        | (po2[1] ^ tgt32) | (po2[3] ^ tgt32) | (po3[1] ^ tgt32) | (po3[3] ^ tgt32)
                        | (po4[1] ^ tgt32) | (po4[3] ^ tgt32) | (po5[1] ^ tgt32) | (po5[3] ^ tgt32)
                        | (po6[1] ^ tgt32) | (po6[3] ^ tgt32) | (po7[1] ^ tgt32) | (po7[3] ^ tgt32);
                }
                const bool ok = ((sh & 0xFFFF0000u) == 0u) && (sf == 0u);
                if (__ballot(ok) == ALL) break;
                if (++it > 20000) break;     // finite-wrong, never hang
                ISSUE1();
            }
#undef ISSUE1
            if (rdA) {
                UNPACK0(va0, tid);       UNPACK0(va1, tid + 128);
                UNPACK0(va2, tid + 256); UNPACK0(va3, tid + 384);
                UNPACK0(va4, tid + 512); UNPACK0(va5, tid + 640);
                UNPACK0(va6, tid + 768); UNPACK0(va7, tid + 896);
            }
            if (rdB) {
                UNPACK1(vb0, tid);       UNPACK1(vb1, tid + 128);
                UNPACK1(vb2, tid + 256); UNPACK1(vb3, tid + 384);
                UNPACK1(vb4, tid + 512); UNPACK1(vb5, tid + 640);
                UNPACK1(vb6, tid + 768); UNPACK1(vb7, tid + 896);
            }
            if (rdP) {                       // assemble out[t = p-1]
                float o = bho;
                o += __uint_as_float(po0[0]) + __uint_as_float(po0[2]);
                o += __uint_as_float(po1[0]) + __uint_as_float(po1[2]);
                o += __uint_as_float(po2[0]) + __uint_as_float(po2[2]);
                o += __uint_as_float(po3[0]) + __uint_as_float(po3[2]);
                o += __uint_as_float(po4[0]) + __uint_as_float(po4[2]);
                o += __uint_as_float(po5[0]) + __uint_as_float(po5[2]);
                o += __uint_as_float(po6[0]) + __uint_as_float(po6[2]);
                o += __uint_as_float(po7[0]) + __uint_as_float(po7[2]);
                out[(bglo + tid) * TT + (p - 1)] = o;
            }
            __syncthreads();                 // LDS planes ready for next phase
        }
    }
}

extern "C" void kernel_launch(void* const* d_in, const int* in_sizes, int n_in,
                              void* d_out, int out_size, void* d_ws, size_t ws_size,
                              hipStream_t stream)
{
    const float* latent = (const float*)d_in[0];
    const float* W_lh   = (const float*)d_in[1];
    const float* b_lh   = (const float*)d_in[2];
    // d_in[3] = W_ih0: unused (layer-0 inputs are all-zero)
    const float* W_hh0  = (const float*)d_in[4];
    const float* b_ih0  = (const float*)d_in[5];
    const float* b_hh0  = (const float*)d_in[6];
    const float* W_ih1  = (const float*)d_in[7];
    const float* W_hh1  = (const float*)d_in[8];
    const float* b_ih1  = (const float*)d_in[9];
    const float* b_hh1  = (const float*)d_in[10];
    const float* W_ho   = (const float*)d_in[11];
    const float* b_ho   = (const float*)d_in[12];

    char* ws = (char*)d_ws;
    u32*   hx0  = (u32*)ws;                       //   524,288 B (2 parities, [stamp16|f16])
    u32*   hx1  = (u32*)(ws + 524288);            //   524,288 B
    u32*   posc = (u32*)(ws + 1048576);           //    65,536 B (2 par x 16g x 512 u32)
    // total 1,114,112 B

    // opt into >64KB dynamic LDS (153,088 B: 128KB wfrag + planes + biases)
    hipFuncSetAttribute((const void*)lstm_wave,
                        hipFuncAttributeMaxDynamicSharedMemorySize, 153088);

    zero_ws<<<dim3(128), dim3(256), 0, stream>>>(hx0, 69632);
    lstm_wave<<<dim3(256), dim3(128), 153088, stream>>>(latent, W_lh, b_lh,
                                                        W_hh0, b_ih0, b_hh0,
                                                        W_ih1, W_hh1, b_ih1, b_hh1,
                                                        W_ho, b_ho,
                                                        hx0, hx1, posc,
                                                        (float*)d_out);
}